// Round 1
// baseline (551.549 us; speedup 1.0000x reference)
//
#include <hip/hip_runtime.h>

#define B_ROWS 32768
#define D_IN   512
#define H1_N   256
#define H2_N   128
#define LAT_N  64
#define K_CB   2048

#define BM 128
#define BN 128
#define BK 32

// XOR swizzle for k-major LDS tiles: spreads transpose-writes across banks,
// keeps 8-wide column groups 16B-aligned for ds_read_b128.
#define SWZ(row) ((((row) >> 2) & 7) << 3)

// MODE 0: out = BN(ReLU(A@W + bias))
// MODE 1: out = A@W + bias
// MODE 2: out = A@W + bias, plus sum((out - xref)^2) partials per block
template <int MODE>
__global__ __launch_bounds__(256, 2) void gemm_fused(
    const float* __restrict__ A, const float* __restrict__ W,
    const float* __restrict__ bias,
    const float* __restrict__ bn_g, const float* __restrict__ bn_b,
    const float* __restrict__ bn_m, const float* __restrict__ bn_v,
    float* __restrict__ out,
    const float* __restrict__ xref, float* __restrict__ partials,
    int M, int N)
{
    __shared__ float sA[BK][BM];
    __shared__ float sB[BK][BN];
    const int tid = threadIdx.x;
    const int tr = tid >> 4;   // 0..15
    const int tc = tid & 15;   // 0..15
    const int row0 = blockIdx.x * BM;
    const int n0   = blockIdx.y * BN;

    float acc[8][8];
#pragma unroll
    for (int i = 0; i < 8; ++i)
#pragma unroll
        for (int j = 0; j < 8; ++j) acc[i][j] = 0.f;

    for (int k0 = 0; k0 < M; k0 += BK) {
        // stage A tile [BM][BK] -> k-major sA[BK][BM] (transposed, swizzled)
#pragma unroll
        for (int it = 0; it < 4; ++it) {
            int s = tid + it * 256;         // 0..1023 float4 slots
            int m = s >> 3;                 // 0..127
            int kq = s & 7;                 // 0..7
            float4 v = *reinterpret_cast<const float4*>(
                &A[(size_t)(row0 + m) * M + k0 + kq * 4]);
            int kk = kq * 4;
            sA[kk + 0][m ^ SWZ(kk + 0)] = v.x;
            sA[kk + 1][m ^ SWZ(kk + 1)] = v.y;
            sA[kk + 2][m ^ SWZ(kk + 2)] = v.z;
            sA[kk + 3][m ^ SWZ(kk + 3)] = v.w;
        }
        // stage W tile [BK][BN] (already k-major, float4 writes)
#pragma unroll
        for (int it = 0; it < 4; ++it) {
            int s = tid + it * 256;
            int k = s >> 5;                 // 0..31
            int nq = s & 31;                // 0..31
            int n = n0 + nq * 4;
            float4 v = make_float4(0.f, 0.f, 0.f, 0.f);
            if (n < N)
                v = *reinterpret_cast<const float4*>(&W[(size_t)(k0 + k) * N + n]);
            *reinterpret_cast<float4*>(&sB[k][nq * 4]) = v;
        }
        __syncthreads();
#pragma unroll 4
        for (int k = 0; k < BK; ++k) {
            int ac = (tr * 8) ^ SWZ(k);
            float4 a0 = *reinterpret_cast<float4*>(&sA[k][ac]);
            float4 a1 = *reinterpret_cast<float4*>(&sA[k][ac + 4]);
            float4 b0 = *reinterpret_cast<float4*>(&sB[k][tc * 8]);
            float4 b1 = *reinterpret_cast<float4*>(&sB[k][tc * 8 + 4]);
            float a[8] = {a0.x, a0.y, a0.z, a0.w, a1.x, a1.y, a1.z, a1.w};
            float b[8] = {b0.x, b0.y, b0.z, b0.w, b1.x, b1.y, b1.z, b1.w};
#pragma unroll
            for (int i = 0; i < 8; ++i)
#pragma unroll
                for (int j = 0; j < 8; ++j)
                    acc[i][j] = fmaf(a[i], b[j], acc[i][j]);
        }
        __syncthreads();
    }

    const int nb = n0 + tc * 8;
    float sq = 0.f;
    if (nb < N) {
        float bi[8], sc[8], sh[8];
#pragma unroll
        for (int j = 0; j < 8; ++j) {
            int n = nb + j;
            bi[j] = bias[n];
            if (MODE == 0) {
                float s = bn_g[n] * rsqrtf(bn_v[n] + 1e-5f);
                sc[j] = s;
                sh[j] = bn_b[n] - bn_m[n] * s;
            }
        }
#pragma unroll
        for (int i = 0; i < 8; ++i) {
            int row = row0 + tr * 8 + i;
            float o[8];
#pragma unroll
            for (int j = 0; j < 8; ++j) {
                float v = acc[i][j] + bi[j];
                if (MODE == 0) {
                    v = v > 0.f ? v : 0.f;
                    v = v * sc[j] + sh[j];
                }
                o[j] = v;
            }
            if (MODE == 2) {
#pragma unroll
                for (int j = 0; j < 8; ++j) {
                    float d = o[j] - xref[(size_t)row * N + nb + j];
                    sq = fmaf(d, d, sq);
                }
            }
            *reinterpret_cast<float4*>(&out[(size_t)row * N + nb]) =
                make_float4(o[0], o[1], o[2], o[3]);
            *reinterpret_cast<float4*>(&out[(size_t)row * N + nb + 4]) =
                make_float4(o[4], o[5], o[6], o[7]);
        }
    }
    if (MODE == 2) {
        __syncthreads();
        float* red = &sA[0][0];
        red[tid] = sq;
        __syncthreads();
        for (int off = 128; off > 0; off >>= 1) {
            if (tid < off) red[tid] += red[tid + off];
            __syncthreads();
        }
        if (tid == 0) partials[blockIdx.y * gridDim.x + blockIdx.x] = red[0];
    }
}

__global__ __launch_bounds__(256) void cnorm_kernel(
    const float* __restrict__ cb, float* __restrict__ cn)
{
    int j = blockIdx.x * 256 + threadIdx.x;
    float s = 0.f;
#pragma unroll
    for (int lq = 0; lq < 16; ++lq) {
        float4 v = *reinterpret_cast<const float4*>(&cb[(size_t)j * LAT_N + lq * 4]);
        s = fmaf(v.x, v.x, s); s = fmaf(v.y, v.y, s);
        s = fmaf(v.z, v.z, s); s = fmaf(v.w, v.w, s);
    }
    cn[j] = s;
}

// VQ: per 128-row block, scan all 2048 codewords (chunks of 128 in LDS),
// argmin of cnorm[j] - 2*dot(z,c); gather z_q; vq-loss partial.
__global__ __launch_bounds__(256, 2) void vq_kernel(
    const float* __restrict__ z, const float* __restrict__ cb,
    const float* __restrict__ cnorm,
    float* __restrict__ zq, float* __restrict__ idxf,
    float* __restrict__ partials)
{
    __shared__ float sZ[LAT_N][128];
    __shared__ float sC[LAT_N][128];
    const int tid = threadIdx.x;
    const int tr = tid >> 4;
    const int tc = tid & 15;
    const int row0 = blockIdx.x * 128;

    // stage z tile [128][64] -> k-major sZ[64][128] (swizzled)
#pragma unroll
    for (int it = 0; it < 8; ++it) {
        int s = tid + it * 256;     // 0..2047
        int m = s >> 4;             // 0..127
        int lq = s & 15;            // 0..15
        float4 v = *reinterpret_cast<const float4*>(
            &z[(size_t)(row0 + m) * LAT_N + lq * 4]);
        int ll = lq * 4;
        sZ[ll + 0][m ^ SWZ(ll + 0)] = v.x;
        sZ[ll + 1][m ^ SWZ(ll + 1)] = v.y;
        sZ[ll + 2][m ^ SWZ(ll + 2)] = v.z;
        sZ[ll + 3][m ^ SWZ(ll + 3)] = v.w;
    }

    float best[8];
    int bidx[8];
#pragma unroll
    for (int i = 0; i < 8; ++i) { best[i] = 3.4e38f; bidx[i] = 0; }

    for (int ch = 0; ch < K_CB / 128; ++ch) {
        int j0 = ch * 128;
        __syncthreads();   // protect sC (and sZ on first iter)
#pragma unroll
        for (int it = 0; it < 8; ++it) {
            int s = tid + it * 256;
            int c = s >> 4;
            int lq = s & 15;
            float4 v = *reinterpret_cast<const float4*>(
                &cb[(size_t)(j0 + c) * LAT_N + lq * 4]);
            int ll = lq * 4;
            sC[ll + 0][c ^ SWZ(ll + 0)] = v.x;
            sC[ll + 1][c ^ SWZ(ll + 1)] = v.y;
            sC[ll + 2][c ^ SWZ(ll + 2)] = v.z;
            sC[ll + 3][c ^ SWZ(ll + 3)] = v.w;
        }
        __syncthreads();
        float acc[8][8];
#pragma unroll
        for (int i = 0; i < 8; ++i)
#pragma unroll
            for (int j = 0; j < 8; ++j) acc[i][j] = 0.f;
#pragma unroll 4
        for (int l = 0; l < LAT_N; ++l) {
            int zc = (tr * 8) ^ SWZ(l);
            int cc = (tc * 8) ^ SWZ(l);
            float4 a0 = *reinterpret_cast<float4*>(&sZ[l][zc]);
            float4 a1 = *reinterpret_cast<float4*>(&sZ[l][zc + 4]);
            float4 b0 = *reinterpret_cast<float4*>(&sC[l][cc]);
            float4 b1 = *reinterpret_cast<float4*>(&sC[l][cc + 4]);
            float a[8] = {a0.x, a0.y, a0.z, a0.w, a1.x, a1.y, a1.z, a1.w};
            float b[8] = {b0.x, b0.y, b0.z, b0.w, b1.x, b1.y, b1.z, b1.w};
#pragma unroll
            for (int i = 0; i < 8; ++i)
#pragma unroll
                for (int j = 0; j < 8; ++j)
                    acc[i][j] = fmaf(a[i], b[j], acc[i][j]);
        }
#pragma unroll
        for (int j = 0; j < 8; ++j) {
            int cj = j0 + tc * 8 + j;
            float cn = cnorm[cj];
#pragma unroll
            for (int i = 0; i < 8; ++i) {
                float d = fmaf(-2.f, acc[i][j], cn);
                if (d < best[i]) { best[i] = d; bidx[i] = cj; }
            }
        }
    }

    // cross-thread argmin reduce (16 candidates per row), via LDS (alias sC)
    __syncthreads();
    float* bv = &sC[0][0];                 // [128][16]
    int* bi = (int*)(&sC[0][0] + 128 * 16);
#pragma unroll
    for (int i = 0; i < 8; ++i) {
        bv[(tr * 8 + i) * 16 + tc] = best[i];
        bi[(tr * 8 + i) * 16 + tc] = bidx[i];
    }
    __syncthreads();
    float vql = 0.f;
    if (tid < 128) {
        int rowl = tid;
        float bb = bv[rowl * 16 + 0];
        int bj = bi[rowl * 16 + 0];
        for (int t = 1; t < 16; ++t) {
            float v = bv[rowl * 16 + t];
            int j = bi[rowl * 16 + t];
            if (v < bb || (v == bb && j < bj)) { bb = v; bj = j; }
        }
        int grow = row0 + rowl;
        idxf[grow] = (float)bj;
#pragma unroll
        for (int lq = 0; lq < 16; ++lq) {
            float4 c = *reinterpret_cast<const float4*>(&cb[(size_t)bj * LAT_N + lq * 4]);
            *reinterpret_cast<float4*>(&zq[(size_t)grow * LAT_N + lq * 4]) = c;
            int ll = lq * 4;
            float z0 = sZ[ll + 0][rowl ^ SWZ(ll + 0)];
            float z1 = sZ[ll + 1][rowl ^ SWZ(ll + 1)];
            float z2 = sZ[ll + 2][rowl ^ SWZ(ll + 2)];
            float z3 = sZ[ll + 3][rowl ^ SWZ(ll + 3)];
            float d0 = c.x - z0, d1 = c.y - z1, d2 = c.z - z2, d3 = c.w - z3;
            vql = fmaf(d0, d0, vql); vql = fmaf(d1, d1, vql);
            vql = fmaf(d2, d2, vql); vql = fmaf(d3, d3, vql);
        }
    }
    __syncthreads();
    float* red = &sC[0][0];
    red[tid] = vql;
    __syncthreads();
    for (int off = 128; off > 0; off >>= 1) {
        if (tid < off) red[tid] += red[tid + off];
        __syncthreads();
    }
    if (tid == 0) partials[blockIdx.x] = red[0];
}

__global__ __launch_bounds__(256) void finalize_kernel(
    const float* __restrict__ vqp, int nvq,
    const float* __restrict__ rep, int nre,
    float* __restrict__ vq_out, float* __restrict__ re_out)
{
    __shared__ float s[256];
    int tid = threadIdx.x;
    float a = 0.f;
    for (int i = tid; i < nvq; i += 256) a += vqp[i];
    s[tid] = a;
    __syncthreads();
    for (int off = 128; off > 0; off >>= 1) {
        if (tid < off) s[tid] += s[tid + off];
        __syncthreads();
    }
    if (tid == 0) *vq_out = 1.25f * s[0] / (float)(B_ROWS * LAT_N);
    __syncthreads();
    float b = 0.f;
    for (int i = tid; i < nre; i += 256) b += rep[i];
    s[tid] = b;
    __syncthreads();
    for (int off = 128; off > 0; off >>= 1) {
        if (tid < off) s[tid] += s[tid + off];
        __syncthreads();
    }
    if (tid == 0) *re_out = s[0] / (float)(B_ROWS * D_IN);
}

extern "C" void kernel_launch(void* const* d_in, const int* in_sizes, int n_in,
                              void* d_out, int out_size, void* d_ws, size_t ws_size,
                              hipStream_t stream)
{
    const float* x    = (const float*)d_in[0];
    const float* ew1  = (const float*)d_in[1];
    const float* eb1  = (const float*)d_in[2];
    const float* eg1  = (const float*)d_in[3];
    const float* ebt1 = (const float*)d_in[4];
    const float* em1  = (const float*)d_in[5];
    const float* ev1  = (const float*)d_in[6];
    const float* ew2  = (const float*)d_in[7];
    const float* eb2  = (const float*)d_in[8];
    const float* eg2  = (const float*)d_in[9];
    const float* ebt2 = (const float*)d_in[10];
    const float* em2  = (const float*)d_in[11];
    const float* ev2  = (const float*)d_in[12];
    const float* ew3  = (const float*)d_in[13];
    const float* eb3  = (const float*)d_in[14];
    const float* cb   = (const float*)d_in[15];
    const float* dw1  = (const float*)d_in[16];
    const float* db1  = (const float*)d_in[17];
    const float* dg1  = (const float*)d_in[18];
    const float* dbt1 = (const float*)d_in[19];
    const float* dm1  = (const float*)d_in[20];
    const float* dv1  = (const float*)d_in[21];
    const float* dw2  = (const float*)d_in[22];
    const float* db2  = (const float*)d_in[23];
    const float* dg2  = (const float*)d_in[24];
    const float* dbt2 = (const float*)d_in[25];
    const float* dm2  = (const float*)d_in[26];
    const float* dv2  = (const float*)d_in[27];
    const float* dw3  = (const float*)d_in[28];
    const float* db3  = (const float*)d_in[29];

    float* outf = (float*)d_out;
    // d_out layout: x_recon [B,512] | vq_loss | idx [B] | recon_err
    const size_t XR_OFF = 0;
    const size_t VQ_OFF = (size_t)B_ROWS * D_IN;
    const size_t IDX_OFF = VQ_OFF + 1;
    const size_t RE_OFF = IDX_OFF + B_ROWS;

    float* wsf = (float*)d_ws;
    size_t off = 0;
    float* buf256 = wsf + off; off += (size_t)B_ROWS * H1_N;   // h1 / d2
    float* buf128 = wsf + off; off += (size_t)B_ROWS * H2_N;   // h2 / d1
    float* zbuf   = wsf + off; off += (size_t)B_ROWS * LAT_N;  // z_e
    float* zqbuf  = wsf + off; off += (size_t)B_ROWS * LAT_N;  // z_q
    float* cnbuf  = wsf + off; off += K_CB;                    // ||c||^2
    float* vqp    = wsf + off; off += 256;                     // vq partials
    float* rep    = wsf + off; off += 1024;                    // recon partials

    dim3 blk(256);
    const int GX = B_ROWS / BM;   // 256

    cnorm_kernel<<<dim3(K_CB / 256), blk, 0, stream>>>(cb, cnbuf);

    // encoder
    gemm_fused<0><<<dim3(GX, H1_N / BN), blk, 0, stream>>>(
        x, ew1, eb1, eg1, ebt1, em1, ev1, buf256, nullptr, nullptr, D_IN, H1_N);
    gemm_fused<0><<<dim3(GX, 1), blk, 0, stream>>>(
        buf256, ew2, eb2, eg2, ebt2, em2, ev2, buf128, nullptr, nullptr, H1_N, H2_N);
    gemm_fused<1><<<dim3(GX, 1), blk, 0, stream>>>(
        buf128, ew3, eb3, nullptr, nullptr, nullptr, nullptr, zbuf, nullptr, nullptr,
        H2_N, LAT_N);

    // vector quantization
    vq_kernel<<<dim3(B_ROWS / 128), blk, 0, stream>>>(
        zbuf, cb, cnbuf, zqbuf, outf + IDX_OFF, vqp);

    // decoder (reuse buffers)
    gemm_fused<0><<<dim3(GX, 1), blk, 0, stream>>>(
        zqbuf, dw1, db1, dg1, dbt1, dm1, dv1, buf128, nullptr, nullptr, LAT_N, H2_N);
    gemm_fused<0><<<dim3(GX, H1_N / BN), blk, 0, stream>>>(
        buf128, dw2, db2, dg2, dbt2, dm2, dv2, buf256, nullptr, nullptr, H2_N, H1_N);
    gemm_fused<2><<<dim3(GX, D_IN / BN), blk, 0, stream>>>(
        buf256, dw3, db3, nullptr, nullptr, nullptr, nullptr, outf + XR_OFF,
        x, rep, H1_N, D_IN);

    finalize_kernel<<<dim3(1), blk, 0, stream>>>(
        vqp, 256, rep, 1024, outf + VQ_OFF, outf + RE_OFF);
}

// Round 4
// 479.704 us; speedup vs baseline: 1.1498x; 1.1498x over previous
//
#include <hip/hip_runtime.h>

#define B_ROWS 32768
#define D_IN   512
#define H1_N   256
#define H2_N   128
#define LAT_N  64
#define K_CB   2048

#define BM 128
#define BN 128
#define BK 32

#define VQ_MARGIN 4.0e-3f

typedef __attribute__((ext_vector_type(8))) short s8v;   // 8 bf16 (4 VGPRs)
typedef __attribute__((ext_vector_type(4))) float f4v;   // 4 f32 acc

__device__ inline unsigned short f2bf(float f) {
    union { float f; unsigned u; } v; v.f = f;
    unsigned r = v.u + 0x7fffu + ((v.u >> 16) & 1u);
    return (unsigned short)(r >> 16);
}
__device__ inline float bf2f(unsigned short h) {
    union { unsigned u; float f; } v; v.u = ((unsigned)h) << 16;
    return v.f;
}

// XOR swizzle for k-major LDS tiles (f32 GEMM path)
#define SWZ(row) ((((row) >> 2) & 7) << 3)

// MODE 0: out = BN(ReLU(A@W + bias))
// MODE 1: out = A@W + bias
// MODE 2: out = A@W + bias, plus sum((out - xref)^2) partials per block
template <int MODE>
__global__ __launch_bounds__(256, 2) void gemm_fused(
    const float* __restrict__ A, const float* __restrict__ W,
    const float* __restrict__ bias,
    const float* __restrict__ bn_g, const float* __restrict__ bn_b,
    const float* __restrict__ bn_m, const float* __restrict__ bn_v,
    float* __restrict__ out,
    const float* __restrict__ xref, float* __restrict__ partials,
    int M, int N)
{
    __shared__ float sA[BK][BM];
    __shared__ float sB[BK][BN];
    const int tid = threadIdx.x;
    const int tr = tid >> 4;   // 0..15
    const int tc = tid & 15;   // 0..15
    const int row0 = blockIdx.x * BM;
    const int n0   = blockIdx.y * BN;

    float acc[8][8];
#pragma unroll
    for (int i = 0; i < 8; ++i)
#pragma unroll
        for (int j = 0; j < 8; ++j) acc[i][j] = 0.f;

    for (int k0 = 0; k0 < M; k0 += BK) {
#pragma unroll
        for (int it = 0; it < 4; ++it) {
            int s = tid + it * 256;
            int m = s >> 3;
            int kq = s & 7;
            float4 v = *reinterpret_cast<const float4*>(
                &A[(size_t)(row0 + m) * M + k0 + kq * 4]);
            int kk = kq * 4;
            sA[kk + 0][m ^ SWZ(kk + 0)] = v.x;
            sA[kk + 1][m ^ SWZ(kk + 1)] = v.y;
            sA[kk + 2][m ^ SWZ(kk + 2)] = v.z;
            sA[kk + 3][m ^ SWZ(kk + 3)] = v.w;
        }
#pragma unroll
        for (int it = 0; it < 4; ++it) {
            int s = tid + it * 256;
            int k = s >> 5;
            int nq = s & 31;
            int n = n0 + nq * 4;
            float4 v = make_float4(0.f, 0.f, 0.f, 0.f);
            if (n < N)
                v = *reinterpret_cast<const float4*>(&W[(size_t)(k0 + k) * N + n]);
            *reinterpret_cast<float4*>(&sB[k][nq * 4]) = v;
        }
        __syncthreads();
#pragma unroll 4
        for (int k = 0; k < BK; ++k) {
            int ac = (tr * 8) ^ SWZ(k);
            float4 a0 = *reinterpret_cast<float4*>(&sA[k][ac]);
            float4 a1 = *reinterpret_cast<float4*>(&sA[k][ac + 4]);
            float4 b0 = *reinterpret_cast<float4*>(&sB[k][tc * 8]);
            float4 b1 = *reinterpret_cast<float4*>(&sB[k][tc * 8 + 4]);
            float a[8] = {a0.x, a0.y, a0.z, a0.w, a1.x, a1.y, a1.z, a1.w};
            float b[8] = {b0.x, b0.y, b0.z, b0.w, b1.x, b1.y, b1.z, b1.w};
#pragma unroll
            for (int i = 0; i < 8; ++i)
#pragma unroll
                for (int j = 0; j < 8; ++j)
                    acc[i][j] = fmaf(a[i], b[j], acc[i][j]);
        }
        __syncthreads();
    }

    const int nb = n0 + tc * 8;
    float sq = 0.f;
    if (nb < N) {
        float bi[8], sc[8], sh[8];
#pragma unroll
        for (int j = 0; j < 8; ++j) {
            int n = nb + j;
            bi[j] = bias[n];
            if (MODE == 0) {
                float s = bn_g[n] * rsqrtf(bn_v[n] + 1e-5f);
                sc[j] = s;
                sh[j] = bn_b[n] - bn_m[n] * s;
            }
        }
#pragma unroll
        for (int i = 0; i < 8; ++i) {
            int row = row0 + tr * 8 + i;
            float o[8];
#pragma unroll
            for (int j = 0; j < 8; ++j) {
                float v = acc[i][j] + bi[j];
                if (MODE == 0) {
                    v = v > 0.f ? v : 0.f;
                    v = v * sc[j] + sh[j];
                }
                o[j] = v;
            }
            if (MODE == 2) {
#pragma unroll
                for (int j = 0; j < 8; ++j) {
                    float d = o[j] - xref[(size_t)row * N + nb + j];
                    sq = fmaf(d, d, sq);
                }
            }
            *reinterpret_cast<float4*>(&out[(size_t)row * N + nb]) =
                make_float4(o[0], o[1], o[2], o[3]);
            *reinterpret_cast<float4*>(&out[(size_t)row * N + nb + 4]) =
                make_float4(o[4], o[5], o[6], o[7]);
        }
    }
    if (MODE == 2) {
        __syncthreads();
        float* red = &sA[0][0];
        red[tid] = sq;
        __syncthreads();
        for (int off = 128; off > 0; off >>= 1) {
            if (tid < off) red[tid] += red[tid + off];
            __syncthreads();
        }
        if (tid == 0) partials[blockIdx.y * gridDim.x + blockIdx.x] = red[0];
    }
}

// codebook -> bf16 hi/lo split + squared norms; also zero repair counter
__global__ __launch_bounds__(256) void vq_prep(
    const float* __restrict__ cb, unsigned short* __restrict__ cb_hi,
    unsigned short* __restrict__ cb_lo, float* __restrict__ cn,
    int* __restrict__ rcnt)
{
    if (blockIdx.x == 0 && threadIdx.x == 0) rcnt[0] = 0;
    int j = blockIdx.x * 256 + threadIdx.x;   // 0..2047
    float s = 0.f;
#pragma unroll
    for (int lq = 0; lq < 16; ++lq) {
        float4 v = *reinterpret_cast<const float4*>(&cb[(size_t)j * LAT_N + lq * 4]);
        float e[4] = {v.x, v.y, v.z, v.w};
        ushort4 h, l;
        unsigned short* hp = &h.x;
        unsigned short* lp = &l.x;
#pragma unroll
        for (int t = 0; t < 4; ++t) {
            s = fmaf(e[t], e[t], s);
            unsigned short hb = f2bf(e[t]);
            hp[t] = hb;
            lp[t] = f2bf(e[t] - bf2f(hb));
        }
        *reinterpret_cast<ushort4*>(&cb_hi[(size_t)j * LAT_N + lq * 4]) = h;
        *reinterpret_cast<ushort4*>(&cb_lo[(size_t)j * LAT_N + lq * 4]) = l;
    }
    cn[j] = s;
}

// VQ scores via bf16x3 MFMA with top-2 tracking.
// wave = 64 rows x 256 codewords; grid 1024x256 = 4096 waves.
__global__ __launch_bounds__(256) void vq_mfma(
    const float* __restrict__ z, const unsigned short* __restrict__ cb_hi,
    const unsigned short* __restrict__ cb_lo, const float* __restrict__ cnorm,
    float4* __restrict__ cand)
{
    const int lane = threadIdx.x & 63;
    const int wid  = blockIdx.x * 4 + (threadIdx.x >> 6);
    const int rbase = (wid >> 3) * 64;
    const int cblk  = wid & 7;
    const int cbase = cblk * 256;
    const int lr = lane & 15;   // A row / B,D col
    const int lg = lane >> 4;   // k-group / D row-group

    s8v a_hi[4][2], a_lo[4][2];
#pragma unroll
    for (int rt = 0; rt < 4; ++rt) {
        int row = rbase + rt * 16 + lr;
#pragma unroll
        for (int ks = 0; ks < 2; ++ks) {
            const float* p = &z[(size_t)row * LAT_N + ks * 32 + lg * 8];
            float4 v0 = *reinterpret_cast<const float4*>(p);
            float4 v1 = *reinterpret_cast<const float4*>(p + 4);
            float vv[8] = {v0.x, v0.y, v0.z, v0.w, v1.x, v1.y, v1.z, v1.w};
#pragma unroll
            for (int jj = 0; jj < 8; ++jj) {
                unsigned short hb = f2bf(vv[jj]);
                a_hi[rt][ks][jj] = (short)hb;
                a_lo[rt][ks][jj] = (short)f2bf(vv[jj] - bf2f(hb));
            }
        }
    }

    float b1[4][4], b2[4][4];
    int j1[4][4];
#pragma unroll
    for (int rt = 0; rt < 4; ++rt)
#pragma unroll
        for (int i = 0; i < 4; ++i) {
            b1[rt][i] = 3.4e38f; b2[rt][i] = 3.4e38f; j1[rt][i] = 0;
        }

    for (int ct = 0; ct < 16; ++ct) {
        int col = cbase + ct * 16 + lr;
        const unsigned short* ph = &cb_hi[(size_t)col * LAT_N + lg * 8];
        const unsigned short* pl = &cb_lo[(size_t)col * LAT_N + lg * 8];
        s8v bh0 = *reinterpret_cast<const s8v*>(ph);
        s8v bh1 = *reinterpret_cast<const s8v*>(ph + 32);
        s8v bl0 = *reinterpret_cast<const s8v*>(pl);
        s8v bl1 = *reinterpret_cast<const s8v*>(pl + 32);
        float cn = cnorm[col];
#pragma unroll
        for (int rt = 0; rt < 4; ++rt) {
            f4v acc = {0.f, 0.f, 0.f, 0.f};
            acc = __builtin_amdgcn_mfma_f32_16x16x32_bf16(a_hi[rt][0], bh0, acc, 0, 0, 0);
            acc = __builtin_amdgcn_mfma_f32_16x16x32_bf16(a_hi[rt][1], bh1, acc, 0, 0, 0);
            acc = __builtin_amdgcn_mfma_f32_16x16x32_bf16(a_lo[rt][0], bh0, acc, 0, 0, 0);
            acc = __builtin_amdgcn_mfma_f32_16x16x32_bf16(a_lo[rt][1], bh1, acc, 0, 0, 0);
            acc = __builtin_amdgcn_mfma_f32_16x16x32_bf16(a_hi[rt][0], bl0, acc, 0, 0, 0);
            acc = __builtin_amdgcn_mfma_f32_16x16x32_bf16(a_hi[rt][1], bl1, acc, 0, 0, 0);
#pragma unroll
            for (int i = 0; i < 4; ++i) {
                float d = fmaf(-2.f, acc[i], cn);
                if (d < b1[rt][i]) {
                    b2[rt][i] = b1[rt][i];
                    b1[rt][i] = d;
                    j1[rt][i] = col;
                } else if (d < b2[rt][i]) {
                    b2[rt][i] = d;
                }
            }
        }
    }

    // top-2 merge across the 16 lanes of each row-group
#pragma unroll
    for (int off = 1; off < 16; off <<= 1) {
#pragma unroll
        for (int rt = 0; rt < 4; ++rt)
#pragma unroll
            for (int i = 0; i < 4; ++i) {
                float o1 = __shfl_xor(b1[rt][i], off);
                float o2 = __shfl_xor(b2[rt][i], off);
                int oj = __shfl_xor(j1[rt][i], off);
                float nb2 = fminf(fmaxf(b1[rt][i], o1), fminf(b2[rt][i], o2));
                if (o1 < b1[rt][i] ||
                    (o1 == b1[rt][i] && oj < j1[rt][i])) {
                    b1[rt][i] = o1;
                    j1[rt][i] = oj;
                }
                b2[rt][i] = nb2;
            }
    }
    if (lr == 0) {
#pragma unroll
        for (int rt = 0; rt < 4; ++rt)
#pragma unroll
            for (int i = 0; i < 4; ++i) {
                int row = rbase + rt * 16 + lg * 4 + i;
                cand[(size_t)row * 8 + cblk] = make_float4(
                    b1[rt][i], __int_as_float(j1[rt][i]), b2[rt][i], 0.f);
            }
    }
}

// merge 8 col-block candidates/row; flag near-ties for exact repair
__global__ __launch_bounds__(256) void vq_merge(
    const float4* __restrict__ cand, float* __restrict__ idxf,
    int* __restrict__ rlist, int* __restrict__ rcnt)
{
    int row = blockIdx.x * 256 + threadIdx.x;
    const float4* c = &cand[(size_t)row * 8];
    float4 c0 = c[0];
    float b1 = c0.x, b2 = c0.z;
    int j1 = __float_as_int(c0.y);
#pragma unroll
    for (int t = 1; t < 8; ++t) {
        float4 ct = c[t];
        float o1 = ct.x, o2 = ct.z;
        int oj = __float_as_int(ct.y);
        float nb2 = fminf(fmaxf(b1, o1), fminf(b2, o2));
        if (o1 < b1 || (o1 == b1 && oj < j1)) { b1 = o1; j1 = oj; }
        b2 = nb2;
    }
    idxf[row] = (float)j1;
    if (!(b2 - b1 >= VQ_MARGIN)) {
        int s = atomicAdd(rcnt, 1);
        if (s < B_ROWS) rlist[s] = row;
    }
}

// exact-f32 full-row rescan of flagged rows (bitwise round-1 semantics)
#define RB 8
__global__ __launch_bounds__(256) void vq_repair(
    const int* __restrict__ rcnt, const int* __restrict__ rlist,
    const float* __restrict__ z, const float* __restrict__ cb,
    const float* __restrict__ cn, float* __restrict__ idxf)
{
    __shared__ float sz[RB][LAT_N];
    __shared__ float rv[256];
    __shared__ int ri[256];
    const int tid = threadIdx.x;
    const int count = min(rcnt[0], B_ROWS);
    for (int base = blockIdx.x * RB; base < count; base += gridDim.x * RB) {
        int nr = min(RB, count - base);
        __syncthreads();
        for (int s = tid; s < nr * LAT_N; s += 256) {
            int r = s >> 6, d = s & 63;
            int rr = rlist[base + r];
            rr = ((unsigned)rr < (unsigned)B_ROWS) ? rr : 0;
            sz[r][d] = z[(size_t)rr * LAT_N + d];
        }
        __syncthreads();
        float bv[RB];
        int bj[RB];
#pragma unroll
        for (int r = 0; r < RB; ++r) { bv[r] = 3.4e38f; bj[r] = 0; }
        for (int k = 0; k < K_CB / 256; ++k) {
            int cidx = tid + k * 256;
            float acc[RB];
#pragma unroll
            for (int r = 0; r < RB; ++r) acc[r] = 0.f;
            const float* cp = &cb[(size_t)cidx * LAT_N];
#pragma unroll
            for (int d4 = 0; d4 < 16; ++d4) {
                float4 cv = *reinterpret_cast<const float4*>(cp + d4 * 4);
#pragma unroll
                for (int r = 0; r < RB; ++r) {
                    acc[r] = fmaf(sz[r][d4 * 4 + 0], cv.x, acc[r]);
                    acc[r] = fmaf(sz[r][d4 * 4 + 1], cv.y, acc[r]);
                    acc[r] = fmaf(sz[r][d4 * 4 + 2], cv.z, acc[r]);
                    acc[r] = fmaf(sz[r][d4 * 4 + 3], cv.w, acc[r]);
                }
            }
            float cnv = cn[cidx];
#pragma unroll
            for (int r = 0; r < RB; ++r) {
                float d = fmaf(-2.f, acc[r], cnv);
                if (d < bv[r] || (d == bv[r] && cidx < bj[r])) {
                    bv[r] = d; bj[r] = cidx;
                }
            }
        }
        for (int r = 0; r < RB; ++r) {
            if (r >= nr) break;
            rv[tid] = bv[r];
            ri[tid] = bj[r];
            __syncthreads();
            for (int off = 128; off > 0; off >>= 1) {
                if (tid < off) {
                    float ov = rv[tid + off];
                    int oi = ri[tid + off];
                    if (ov < rv[tid] || (ov == rv[tid] && oi < ri[tid])) {
                        rv[tid] = ov; ri[tid] = oi;
                    }
                }
                __syncthreads();
            }
            if (tid == 0) {
                int rr = rlist[base + r];
                if ((unsigned)rr < (unsigned)B_ROWS)
                    idxf[rr] = (float)ri[0];
            }
            __syncthreads();
        }
    }
}

// gather z_q from final idx + vq-loss partials
__global__ __launch_bounds__(256) void vq_zqloss(
    const float* __restrict__ idxf, const float* __restrict__ z,
    const float* __restrict__ cb, float* __restrict__ zq,
    float* __restrict__ partials)
{
    __shared__ float red[256];
    int tid = threadIdx.x;
    int row = blockIdx.x * 256 + tid;
    int bj = (int)idxf[row];
    bj = ((unsigned)bj < (unsigned)K_CB) ? bj : 0;
    float sq = 0.f;
#pragma unroll
    for (int lq = 0; lq < 16; ++lq) {
        float4 cv = *reinterpret_cast<const float4*>(&cb[(size_t)bj * LAT_N + lq * 4]);
        float4 zv = *reinterpret_cast<const float4*>(&z[(size_t)row * LAT_N + lq * 4]);
        *reinterpret_cast<float4*>(&zq[(size_t)row * LAT_N + lq * 4]) = cv;
        float d0 = cv.x - zv.x, d1 = cv.y - zv.y;
        float d2 = cv.z - zv.z, d3 = cv.w - zv.w;
        sq = fmaf(d0, d0, sq); sq = fmaf(d1, d1, sq);
        sq = fmaf(d2, d2, sq); sq = fmaf(d3, d3, sq);
    }
    red[tid] = sq;
    __syncthreads();
    for (int off = 128; off > 0; off >>= 1) {
        if (tid < off) red[tid] += red[tid + off];
        __syncthreads();
    }
    if (tid == 0) partials[blockIdx.x] = red[0];
}

__global__ __launch_bounds__(256) void finalize_kernel(
    const float* __restrict__ vqp, int nvq,
    const float* __restrict__ rep, int nre,
    float* __restrict__ vq_out, float* __restrict__ re_out)
{
    __shared__ float s[256];
    int tid = threadIdx.x;
    float a = 0.f;
    for (int i = tid; i < nvq; i += 256) a += vqp[i];
    s[tid] = a;
    __syncthreads();
    for (int off = 128; off > 0; off >>= 1) {
        if (tid < off) s[tid] += s[tid + off];
        __syncthreads();
    }
    if (tid == 0) *vq_out = 1.25f * s[0] / (float)(B_ROWS * LAT_N);
    __syncthreads();
    float b = 0.f;
    for (int i = tid; i < nre; i += 256) b += rep[i];
    s[tid] = b;
    __syncthreads();
    for (int off = 128; off > 0; off >>= 1) {
        if (tid < off) s[tid] += s[tid + off];
        __syncthreads();
    }
    if (tid == 0) *re_out = s[0] / (float)(B_ROWS * D_IN);
}

extern "C" void kernel_launch(void* const* d_in, const int* in_sizes, int n_in,
                              void* d_out, int out_size, void* d_ws, size_t ws_size,
                              hipStream_t stream)
{
    const float* x    = (const float*)d_in[0];
    const float* ew1  = (const float*)d_in[1];
    const float* eb1  = (const float*)d_in[2];
    const float* eg1  = (const float*)d_in[3];
    const float* ebt1 = (const float*)d_in[4];
    const float* em1  = (const float*)d_in[5];
    const float* ev1  = (const float*)d_in[6];
    const float* ew2  = (const float*)d_in[7];
    const float* eb2  = (const float*)d_in[8];
    const float* eg2  = (const float*)d_in[9];
    const float* ebt2 = (const float*)d_in[10];
    const float* em2  = (const float*)d_in[11];
    const float* ev2  = (const float*)d_in[12];
    const float* ew3  = (const float*)d_in[13];
    const float* eb3  = (const float*)d_in[14];
    const float* cb   = (const float*)d_in[15];
    const float* dw1  = (const float*)d_in[16];
    const float* db1  = (const float*)d_in[17];
    const float* dg1  = (const float*)d_in[18];
    const float* dbt1 = (const float*)d_in[19];
    const float* dm1  = (const float*)d_in[20];
    const float* dv1  = (const float*)d_in[21];
    const float* dw2  = (const float*)d_in[22];
    const float* db2  = (const float*)d_in[23];
    const float* dg2  = (const float*)d_in[24];
    const float* dbt2 = (const float*)d_in[25];
    const float* dm2  = (const float*)d_in[26];
    const float* dv2  = (const float*)d_in[27];
    const float* dw3  = (const float*)d_in[28];
    const float* db3  = (const float*)d_in[29];

    float* outf = (float*)d_out;
    const size_t XR_OFF = 0;
    const size_t VQ_OFF = (size_t)B_ROWS * D_IN;
    const size_t IDX_OFF = VQ_OFF + 1;
    const size_t RE_OFF = IDX_OFF + B_ROWS;

    float* wsf = (float*)d_ws;
    size_t off = 0;
    float* buf256 = wsf + off; off += (size_t)B_ROWS * H1_N;
    float* buf128 = wsf + off; off += (size_t)B_ROWS * H2_N;
    float* zbuf   = wsf + off; off += (size_t)B_ROWS * LAT_N;
    float* zqbuf  = wsf + off; off += (size_t)B_ROWS * LAT_N;
    float* cnbuf  = wsf + off; off += K_CB;
    float* vqp    = wsf + off; off += 128;
    float* rep    = wsf + off; off += 1024;
    unsigned short* cbhi = (unsigned short*)(wsf + off); off += K_CB * LAT_N / 2;
    unsigned short* cblo = (unsigned short*)(wsf + off); off += K_CB * LAT_N / 2;
    float4* candb = (float4*)(wsf + off); off += (size_t)B_ROWS * 8 * 4;  // B*8 float4
    int* rcnt  = (int*)(wsf + off); off += 16;
    int* rlist = (int*)(wsf + off); off += B_ROWS;

    dim3 blk(256);
    const int GX = B_ROWS / BM;   // 256

    vq_prep<<<dim3(K_CB / 256), blk, 0, stream>>>(cb, cbhi, cblo, cnbuf, rcnt);

    // encoder (must stay exact f32: z_e feeds the argmin)
    gemm_fused<0><<<dim3(GX, H1_N / BN), blk, 0, stream>>>(
        x, ew1, eb1, eg1, ebt1, em1, ev1, buf256, nullptr, nullptr, D_IN, H1_N);
    gemm_fused<0><<<dim3(GX, 1), blk, 0, stream>>>(
        buf256, ew2, eb2, eg2, ebt2, em2, ev2, buf128, nullptr, nullptr, H1_N, H2_N);
    gemm_fused<1><<<dim3(GX, 1), blk, 0, stream>>>(
        buf128, ew3, eb3, nullptr, nullptr, nullptr, nullptr, zbuf, nullptr, nullptr,
        H2_N, LAT_N);

    // vector quantization: MFMA top-2 -> merge/flag -> exact repair -> gather
    vq_mfma<<<dim3(1024), blk, 0, stream>>>(zbuf, cbhi, cblo, cnbuf, candb);
    vq_merge<<<dim3(B_ROWS / 256), blk, 0, stream>>>(
        candb, outf + IDX_OFF, rlist, rcnt);
    vq_repair<<<dim3(128), blk, 0, stream>>>(
        rcnt, rlist, zbuf, cb, cnbuf, outf + IDX_OFF);
    vq_zqloss<<<dim3(B_ROWS / 256), blk, 0, stream>>>(
        outf + IDX_OFF, zbuf, cb, zqbuf, vqp);

    // decoder
    gemm_fused<0><<<dim3(GX, 1), blk, 0, stream>>>(
        zqbuf, dw1, db1, dg1, dbt1, dm1, dv1, buf128, nullptr, nullptr, LAT_N, H2_N);
    gemm_fused<0><<<dim3(GX, H1_N / BN), blk, 0, stream>>>(
        buf128, dw2, db2, dg2, dbt2, dm2, dv2, buf256, nullptr, nullptr, H2_N, H1_N);
    gemm_fused<2><<<dim3(GX, D_IN / BN), blk, 0, stream>>>(
        buf256, dw3, db3, nullptr, nullptr, nullptr, nullptr, outf + XR_OFF,
        x, rep, H1_N, D_IN);

    finalize_kernel<<<dim3(1), blk, 0, stream>>>(
        vqp, 128, rep, 1024, outf + VQ_OFF, outf + RE_OFF);
}

// Round 5
// 439.541 us; speedup vs baseline: 1.2548x; 1.0914x over previous
//
#include <hip/hip_runtime.h>

#define B_ROWS 32768
#define D_IN   512
#define H1_N   256
#define H2_N   128
#define LAT_N  64
#define K_CB   2048

#define BM 128
#define BN 128
#define BK 32

#define VQ_MARGIN 4.0e-3f

typedef __attribute__((ext_vector_type(8))) short s8v;   // 8 bf16 (4 VGPRs)
typedef __attribute__((ext_vector_type(4))) float f4v;   // 4 f32 acc

__device__ inline unsigned short f2bf(float f) {
    union { float f; unsigned u; } v; v.f = f;
    unsigned r = v.u + 0x7fffu + ((v.u >> 16) & 1u);
    return (unsigned short)(r >> 16);
}
__device__ inline float bf2f(unsigned short h) {
    union { unsigned u; float f; } v; v.u = ((unsigned)h) << 16;
    return v.f;
}

// XOR swizzle for k-major LDS tiles (f32 GEMM path)
#define SWZ(row) ((((row) >> 2) & 7) << 3)

// ---------------- f32 GEMM (encoder only now) ----------------
// MODE 0: out = BN(ReLU(A@W + bias))
// MODE 1: out = A@W + bias
template <int MODE>
__global__ __launch_bounds__(256, 2) void gemm_fused(
    const float* __restrict__ A, const float* __restrict__ W,
    const float* __restrict__ bias,
    const float* __restrict__ bn_g, const float* __restrict__ bn_b,
    const float* __restrict__ bn_m, const float* __restrict__ bn_v,
    float* __restrict__ out,
    const float* __restrict__ xref, float* __restrict__ partials,
    int M, int N)
{
    __shared__ float sA[BK][BM];
    __shared__ float sB[BK][BN];
    const int tid = threadIdx.x;
    const int tr = tid >> 4;   // 0..15
    const int tc = tid & 15;   // 0..15
    const int row0 = blockIdx.x * BM;
    const int n0   = blockIdx.y * BN;

    float acc[8][8];
#pragma unroll
    for (int i = 0; i < 8; ++i)
#pragma unroll
        for (int j = 0; j < 8; ++j) acc[i][j] = 0.f;

    for (int k0 = 0; k0 < M; k0 += BK) {
#pragma unroll
        for (int it = 0; it < 4; ++it) {
            int s = tid + it * 256;
            int m = s >> 3;
            int kq = s & 7;
            float4 v = *reinterpret_cast<const float4*>(
                &A[(size_t)(row0 + m) * M + k0 + kq * 4]);
            int kk = kq * 4;
            sA[kk + 0][m ^ SWZ(kk + 0)] = v.x;
            sA[kk + 1][m ^ SWZ(kk + 1)] = v.y;
            sA[kk + 2][m ^ SWZ(kk + 2)] = v.z;
            sA[kk + 3][m ^ SWZ(kk + 3)] = v.w;
        }
#pragma unroll
        for (int it = 0; it < 4; ++it) {
            int s = tid + it * 256;
            int k = s >> 5;
            int nq = s & 31;
            int n = n0 + nq * 4;
            float4 v = make_float4(0.f, 0.f, 0.f, 0.f);
            if (n < N)
                v = *reinterpret_cast<const float4*>(&W[(size_t)(k0 + k) * N + n]);
            *reinterpret_cast<float4*>(&sB[k][nq * 4]) = v;
        }
        __syncthreads();
#pragma unroll 4
        for (int k = 0; k < BK; ++k) {
            int ac = (tr * 8) ^ SWZ(k);
            float4 a0 = *reinterpret_cast<float4*>(&sA[k][ac]);
            float4 a1 = *reinterpret_cast<float4*>(&sA[k][ac + 4]);
            float4 b0 = *reinterpret_cast<float4*>(&sB[k][tc * 8]);
            float4 b1 = *reinterpret_cast<float4*>(&sB[k][tc * 8 + 4]);
            float a[8] = {a0.x, a0.y, a0.z, a0.w, a1.x, a1.y, a1.z, a1.w};
            float b[8] = {b0.x, b0.y, b0.z, b0.w, b1.x, b1.y, b1.z, b1.w};
#pragma unroll
            for (int i = 0; i < 8; ++i)
#pragma unroll
                for (int j = 0; j < 8; ++j)
                    acc[i][j] = fmaf(a[i], b[j], acc[i][j]);
        }
        __syncthreads();
    }

    const int nb = n0 + tc * 8;
    if (nb < N) {
        float bi[8], sc[8], sh[8];
#pragma unroll
        for (int j = 0; j < 8; ++j) {
            int n = nb + j;
            bi[j] = bias[n];
            if (MODE == 0) {
                float s = bn_g[n] * rsqrtf(bn_v[n] + 1e-5f);
                sc[j] = s;
                sh[j] = bn_b[n] - bn_m[n] * s;
            }
        }
#pragma unroll
        for (int i = 0; i < 8; ++i) {
            int row = row0 + tr * 8 + i;
            float o[8];
#pragma unroll
            for (int j = 0; j < 8; ++j) {
                float v = acc[i][j] + bi[j];
                if (MODE == 0) {
                    v = v > 0.f ? v : 0.f;
                    v = v * sc[j] + sh[j];
                }
                o[j] = v;
            }
            *reinterpret_cast<float4*>(&out[(size_t)row * N + nb]) =
                make_float4(o[0], o[1], o[2], o[3]);
            *reinterpret_cast<float4*>(&out[(size_t)row * N + nb + 4]) =
                make_float4(o[4], o[5], o[6], o[7]);
        }
    }
}

// ---------------- decoder weight prep: [K][N] f32 -> [N][K] bf16 hi/lo ----
__global__ __launch_bounds__(256) void wprep(
    const float* __restrict__ w, unsigned short* __restrict__ w_hi,
    unsigned short* __restrict__ w_lo, int K, int N)
{
    int idx = blockIdx.x * 256 + threadIdx.x;
    if (idx >= N * K) return;
    int n = idx / K, k = idx - n * K;
    float f = w[(size_t)k * N + n];
    unsigned u = __float_as_uint(f);
    float lo = f - __uint_as_float(u & 0xffff0000u);
    w_hi[idx] = (unsigned short)(u >> 16);
    w_lo[idx] = (unsigned short)(__float_as_uint(lo) >> 16);
}

// ---------------- MFMA decoder GEMM (bf16x3 split precision) ----------
// MODE 0: out = BN(ReLU(A@W+b));  MODE 2: out = A@W+b, + (out-x)^2 partials
template <int MODE, int K>
__global__ __launch_bounds__(256, 2) void mfma_gemm(
    const float* __restrict__ A,
    const unsigned short* __restrict__ w_hi,
    const unsigned short* __restrict__ w_lo,
    const float* __restrict__ bias,
    const float* __restrict__ bn_g, const float* __restrict__ bn_b,
    const float* __restrict__ bn_m, const float* __restrict__ bn_v,
    float* __restrict__ out,
    const float* __restrict__ xref, float* __restrict__ partials, int N)
{
    const int lane = threadIdx.x & 63;
    const int wv = threadIdx.x >> 6;          // 0..3
    const int wr = wv >> 1, wc = wv & 1;      // 2x2 waves over 128x128
    const int rbase = blockIdx.x * 128 + wr * 64;
    const int cbase = blockIdx.y * 128 + wc * 64;
    const int lr = lane & 15, lg = lane >> 4;

    f4v acc[4][4];
#pragma unroll
    for (int rt = 0; rt < 4; ++rt)
#pragma unroll
        for (int ct = 0; ct < 4; ++ct)
            acc[rt][ct] = (f4v){0.f, 0.f, 0.f, 0.f};

#pragma unroll
    for (int ks = 0; ks < K / 32; ++ks) {
        s8v ah[4], al[4], bh[4], bl[4];
#pragma unroll
        for (int rt = 0; rt < 4; ++rt) {
            const float* p =
                &A[(size_t)(rbase + rt * 16 + lr) * K + ks * 32 + lg * 8];
            float4 v0 = *reinterpret_cast<const float4*>(p);
            float4 v1 = *reinterpret_cast<const float4*>(p + 4);
            float fv[8] = {v0.x, v0.y, v0.z, v0.w, v1.x, v1.y, v1.z, v1.w};
            unsigned uu[8], ll[8];
#pragma unroll
            for (int j = 0; j < 8; ++j) {
                uu[j] = __float_as_uint(fv[j]);
                float lo = fv[j] - __uint_as_float(uu[j] & 0xffff0000u);
                ll[j] = __float_as_uint(lo);
            }
            union { s8v v; unsigned w[4]; } H, L;
#pragma unroll
            for (int m = 0; m < 4; ++m) {
                H.w[m] = __builtin_amdgcn_perm(uu[2 * m + 1], uu[2 * m], 0x07060302u);
                L.w[m] = __builtin_amdgcn_perm(ll[2 * m + 1], ll[2 * m], 0x07060302u);
            }
            ah[rt] = H.v;
            al[rt] = L.v;
        }
#pragma unroll
        for (int ct = 0; ct < 4; ++ct) {
            size_t off = (size_t)(cbase + ct * 16 + lr) * K + ks * 32 + lg * 8;
            bh[ct] = *reinterpret_cast<const s8v*>(&w_hi[off]);
            bl[ct] = *reinterpret_cast<const s8v*>(&w_lo[off]);
        }
#pragma unroll
        for (int rt = 0; rt < 4; ++rt)
#pragma unroll
            for (int ct = 0; ct < 4; ++ct) {
                acc[rt][ct] = __builtin_amdgcn_mfma_f32_16x16x32_bf16(
                    ah[rt], bh[ct], acc[rt][ct], 0, 0, 0);
                acc[rt][ct] = __builtin_amdgcn_mfma_f32_16x16x32_bf16(
                    al[rt], bh[ct], acc[rt][ct], 0, 0, 0);
                acc[rt][ct] = __builtin_amdgcn_mfma_f32_16x16x32_bf16(
                    ah[rt], bl[ct], acc[rt][ct], 0, 0, 0);
            }
    }

    float sq = 0.f;
#pragma unroll
    for (int ct = 0; ct < 4; ++ct) {
        int col = cbase + ct * 16 + lr;
        float bi = bias[col];
        float sc = 0.f, sh = 0.f;
        if (MODE == 0) {
            float s = bn_g[col] * rsqrtf(bn_v[col] + 1e-5f);
            sc = s;
            sh = bn_b[col] - bn_m[col] * s;
        }
#pragma unroll
        for (int rt = 0; rt < 4; ++rt)
#pragma unroll
            for (int i = 0; i < 4; ++i) {
                int row = rbase + rt * 16 + lg * 4 + i;
                float v = acc[rt][ct][i] + bi;
                if (MODE == 0) v = fmaxf(v, 0.f) * sc + sh;
                if (MODE == 2) {
                    float d = v - xref[(size_t)row * N + col];
                    sq = fmaf(d, d, sq);
                }
                out[(size_t)row * N + col] = v;
            }
    }
    if (MODE == 2) {
        __shared__ float red[256];
        red[threadIdx.x] = sq;
        __syncthreads();
        for (int off = 128; off > 0; off >>= 1) {
            if (threadIdx.x < off) red[threadIdx.x] += red[threadIdx.x + off];
            __syncthreads();
        }
        if (threadIdx.x == 0)
            partials[blockIdx.y * gridDim.x + blockIdx.x] = red[0];
    }
}

// codebook -> bf16 hi/lo split + squared norms; also zero repair counter
__global__ __launch_bounds__(256) void vq_prep(
    const float* __restrict__ cb, unsigned short* __restrict__ cb_hi,
    unsigned short* __restrict__ cb_lo, float* __restrict__ cn,
    int* __restrict__ rcnt)
{
    if (blockIdx.x == 0 && threadIdx.x == 0) rcnt[0] = 0;
    int j = blockIdx.x * 256 + threadIdx.x;   // 0..2047
    float s = 0.f;
#pragma unroll
    for (int lq = 0; lq < 16; ++lq) {
        float4 v = *reinterpret_cast<const float4*>(&cb[(size_t)j * LAT_N + lq * 4]);
        float e[4] = {v.x, v.y, v.z, v.w};
        ushort4 h, l;
        unsigned short* hp = &h.x;
        unsigned short* lp = &l.x;
#pragma unroll
        for (int t = 0; t < 4; ++t) {
            s = fmaf(e[t], e[t], s);
            unsigned short hb = f2bf(e[t]);
            hp[t] = hb;
            lp[t] = f2bf(e[t] - bf2f(hb));
        }
        *reinterpret_cast<ushort4*>(&cb_hi[(size_t)j * LAT_N + lq * 4]) = h;
        *reinterpret_cast<ushort4*>(&cb_lo[(size_t)j * LAT_N + lq * 4]) = l;
    }
    cn[j] = s;
}

// VQ scores via bf16x3 MFMA with top-2 tracking.
__global__ __launch_bounds__(256) void vq_mfma(
    const float* __restrict__ z, const unsigned short* __restrict__ cb_hi,
    const unsigned short* __restrict__ cb_lo, const float* __restrict__ cnorm,
    float4* __restrict__ cand)
{
    const int lane = threadIdx.x & 63;
    const int wid  = blockIdx.x * 4 + (threadIdx.x >> 6);
    const int rbase = (wid >> 3) * 64;
    const int cblk  = wid & 7;
    const int cbase = cblk * 256;
    const int lr = lane & 15;
    const int lg = lane >> 4;

    s8v a_hi[4][2], a_lo[4][2];
#pragma unroll
    for (int rt = 0; rt < 4; ++rt) {
        int row = rbase + rt * 16 + lr;
#pragma unroll
        for (int ks = 0; ks < 2; ++ks) {
            const float* p = &z[(size_t)row * LAT_N + ks * 32 + lg * 8];
            float4 v0 = *reinterpret_cast<const float4*>(p);
            float4 v1 = *reinterpret_cast<const float4*>(p + 4);
            float vv[8] = {v0.x, v0.y, v0.z, v0.w, v1.x, v1.y, v1.z, v1.w};
#pragma unroll
            for (int jj = 0; jj < 8; ++jj) {
                unsigned short hb = f2bf(vv[jj]);
                a_hi[rt][ks][jj] = (short)hb;
                a_lo[rt][ks][jj] = (short)f2bf(vv[jj] - bf2f(hb));
            }
        }
    }

    float b1[4][4], b2[4][4];
    int j1[4][4];
#pragma unroll
    for (int rt = 0; rt < 4; ++rt)
#pragma unroll
        for (int i = 0; i < 4; ++i) {
            b1[rt][i] = 3.4e38f; b2[rt][i] = 3.4e38f; j1[rt][i] = 0;
        }

    for (int ct = 0; ct < 16; ++ct) {
        int col = cbase + ct * 16 + lr;
        const unsigned short* ph = &cb_hi[(size_t)col * LAT_N + lg * 8];
        const unsigned short* pl = &cb_lo[(size_t)col * LAT_N + lg * 8];
        s8v bh0 = *reinterpret_cast<const s8v*>(ph);
        s8v bh1 = *reinterpret_cast<const s8v*>(ph + 32);
        s8v bl0 = *reinterpret_cast<const s8v*>(pl);
        s8v bl1 = *reinterpret_cast<const s8v*>(pl + 32);
        float cn = cnorm[col];
#pragma unroll
        for (int rt = 0; rt < 4; ++rt) {
            f4v acc = {0.f, 0.f, 0.f, 0.f};
            acc = __builtin_amdgcn_mfma_f32_16x16x32_bf16(a_hi[rt][0], bh0, acc, 0, 0, 0);
            acc = __builtin_amdgcn_mfma_f32_16x16x32_bf16(a_hi[rt][1], bh1, acc, 0, 0, 0);
            acc = __builtin_amdgcn_mfma_f32_16x16x32_bf16(a_lo[rt][0], bh0, acc, 0, 0, 0);
            acc = __builtin_amdgcn_mfma_f32_16x16x32_bf16(a_lo[rt][1], bh1, acc, 0, 0, 0);
            acc = __builtin_amdgcn_mfma_f32_16x16x32_bf16(a_hi[rt][0], bl0, acc, 0, 0, 0);
            acc = __builtin_amdgcn_mfma_f32_16x16x32_bf16(a_hi[rt][1], bl1, acc, 0, 0, 0);
#pragma unroll
            for (int i = 0; i < 4; ++i) {
                float d = fmaf(-2.f, acc[i], cn);
                if (d < b1[rt][i]) {
                    b2[rt][i] = b1[rt][i];
                    b1[rt][i] = d;
                    j1[rt][i] = col;
                } else if (d < b2[rt][i]) {
                    b2[rt][i] = d;
                }
            }
        }
    }

#pragma unroll
    for (int off = 1; off < 16; off <<= 1) {
#pragma unroll
        for (int rt = 0; rt < 4; ++rt)
#pragma unroll
            for (int i = 0; i < 4; ++i) {
                float o1 = __shfl_xor(b1[rt][i], off);
                float o2 = __shfl_xor(b2[rt][i], off);
                int oj = __shfl_xor(j1[rt][i], off);
                float nb2 = fminf(fmaxf(b1[rt][i], o1), fminf(b2[rt][i], o2));
                if (o1 < b1[rt][i] ||
                    (o1 == b1[rt][i] && oj < j1[rt][i])) {
                    b1[rt][i] = o1;
                    j1[rt][i] = oj;
                }
                b2[rt][i] = nb2;
            }
    }
    if (lr == 0) {
#pragma unroll
        for (int rt = 0; rt < 4; ++rt)
#pragma unroll
            for (int i = 0; i < 4; ++i) {
                int row = rbase + rt * 16 + lg * 4 + i;
                cand[(size_t)row * 8 + cblk] = make_float4(
                    b1[rt][i], __int_as_float(j1[rt][i]), b2[rt][i], 0.f);
            }
    }
}

// merge 8 col-block candidates/row; flag near-ties for exact repair
__global__ __launch_bounds__(256) void vq_merge(
    const float4* __restrict__ cand, float* __restrict__ idxf,
    int* __restrict__ rlist, int* __restrict__ rcnt)
{
    int row = blockIdx.x * 256 + threadIdx.x;
    const float4* c = &cand[(size_t)row * 8];
    float4 c0 = c[0];
    float b1 = c0.x, b2 = c0.z;
    int j1 = __float_as_int(c0.y);
#pragma unroll
    for (int t = 1; t < 8; ++t) {
        float4 ct = c[t];
        float o1 = ct.x, o2 = ct.z;
        int oj = __float_as_int(ct.y);
        float nb2 = fminf(fmaxf(b1, o1), fminf(b2, o2));
        if (o1 < b1 || (o1 == b1 && oj < j1)) { b1 = o1; j1 = oj; }
        b2 = nb2;
    }
    idxf[row] = (float)j1;
    if (!(b2 - b1 >= VQ_MARGIN)) {
        int s = atomicAdd(rcnt, 1);
        if (s < B_ROWS) rlist[s] = row;
    }
}

// exact-f32 full-row rescan of flagged rows
#define RB 8
__global__ __launch_bounds__(256) void vq_repair(
    const int* __restrict__ rcnt, const int* __restrict__ rlist,
    const float* __restrict__ z, const float* __restrict__ cb,
    const float* __restrict__ cn, float* __restrict__ idxf)
{
    __shared__ float sz[RB][LAT_N];
    __shared__ float rv[256];
    __shared__ int ri[256];
    const int tid = threadIdx.x;
    const int count = min(rcnt[0], B_ROWS);
    for (int base = blockIdx.x * RB; base < count; base += gridDim.x * RB) {
        int nr = min(RB, count - base);
        __syncthreads();
        for (int s = tid; s < nr * LAT_N; s += 256) {
            int r = s >> 6, d = s & 63;
            int rr = rlist[base + r];
            rr = ((unsigned)rr < (unsigned)B_ROWS) ? rr : 0;
            sz[r][d] = z[(size_t)rr * LAT_N + d];
        }
        __syncthreads();
        float bv[RB];
        int bj[RB];
#pragma unroll
        for (int r = 0; r < RB; ++r) { bv[r] = 3.4e38f; bj[r] = 0; }
        for (int k = 0; k < K_CB / 256; ++k) {
            int cidx = tid + k * 256;
            float acc[RB];
#pragma unroll
            for (int r = 0; r < RB; ++r) acc[r] = 0.f;
            const float* cp = &cb[(size_t)cidx * LAT_N];
#pragma unroll
            for (int d4 = 0; d4 < 16; ++d4) {
                float4 cv = *reinterpret_cast<const float4*>(cp + d4 * 4);
#pragma unroll
                for (int r = 0; r < RB; ++r) {
                    acc[r] = fmaf(sz[r][d4 * 4 + 0], cv.x, acc[r]);
                    acc[r] = fmaf(sz[r][d4 * 4 + 1], cv.y, acc[r]);
                    acc[r] = fmaf(sz[r][d4 * 4 + 2], cv.z, acc[r]);
                    acc[r] = fmaf(sz[r][d4 * 4 + 3], cv.w, acc[r]);
                }
            }
            float cnv = cn[cidx];
#pragma unroll
            for (int r = 0; r < RB; ++r) {
                float d = fmaf(-2.f, acc[r], cnv);
                if (d < bv[r] || (d == bv[r] && cidx < bj[r])) {
                    bv[r] = d; bj[r] = cidx;
                }
            }
        }
        for (int r = 0; r < RB; ++r) {
            if (r >= nr) break;
            rv[tid] = bv[r];
            ri[tid] = bj[r];
            __syncthreads();
            for (int off = 128; off > 0; off >>= 1) {
                if (tid < off) {
                    float ov = rv[tid + off];
                    int oi = ri[tid + off];
                    if (ov < rv[tid] || (ov == rv[tid] && oi < ri[tid])) {
                        rv[tid] = ov; ri[tid] = oi;
                    }
                }
                __syncthreads();
            }
            if (tid == 0) {
                int rr = rlist[base + r];
                if ((unsigned)rr < (unsigned)B_ROWS)
                    idxf[rr] = (float)ri[0];
            }
            __syncthreads();
        }
    }
}

// gather z_q from final idx + vq-loss partials
__global__ __launch_bounds__(256) void vq_zqloss(
    const float* __restrict__ idxf, const float* __restrict__ z,
    const float* __restrict__ cb, float* __restrict__ zq,
    float* __restrict__ partials)
{
    __shared__ float red[256];
    int tid = threadIdx.x;
    int row = blockIdx.x * 256 + tid;
    int bj = (int)idxf[row];
    bj = ((unsigned)bj < (unsigned)K_CB) ? bj : 0;
    float sq = 0.f;
#pragma unroll
    for (int lq = 0; lq < 16; ++lq) {
        float4 cv = *reinterpret_cast<const float4*>(&cb[(size_t)bj * LAT_N + lq * 4]);
        float4 zv = *reinterpret_cast<const float4*>(&z[(size_t)row * LAT_N + lq * 4]);
        *reinterpret_cast<float4*>(&zq[(size_t)row * LAT_N + lq * 4]) = cv;
        float d0 = cv.x - zv.x, d1 = cv.y - zv.y;
        float d2 = cv.z - zv.z, d3 = cv.w - zv.w;
        sq = fmaf(d0, d0, sq); sq = fmaf(d1, d1, sq);
        sq = fmaf(d2, d2, sq); sq = fmaf(d3, d3, sq);
    }
    red[tid] = sq;
    __syncthreads();
    for (int off = 128; off > 0; off >>= 1) {
        if (tid < off) red[tid] += red[tid + off];
        __syncthreads();
    }
    if (tid == 0) partials[blockIdx.x] = red[0];
}

__global__ __launch_bounds__(256) void finalize_kernel(
    const float* __restrict__ vqp, int nvq,
    const float* __restrict__ rep, int nre,
    float* __restrict__ vq_out, float* __restrict__ re_out)
{
    __shared__ float s[256];
    int tid = threadIdx.x;
    float a = 0.f;
    for (int i = tid; i < nvq; i += 256) a += vqp[i];
    s[tid] = a;
    __syncthreads();
    for (int off = 128; off > 0; off >>= 1) {
        if (tid < off) s[tid] += s[tid + off];
        __syncthreads();
    }
    if (tid == 0) *vq_out = 1.25f * s[0] / (float)(B_ROWS * LAT_N);
    __syncthreads();
    float b = 0.f;
    for (int i = tid; i < nre; i += 256) b += rep[i];
    s[tid] = b;
    __syncthreads();
    for (int off = 128; off > 0; off >>= 1) {
        if (tid < off) s[tid] += s[tid + off];
        __syncthreads();
    }
    if (tid == 0) *re_out = s[0] / (float)(B_ROWS * D_IN);
}

extern "C" void kernel_launch(void* const* d_in, const int* in_sizes, int n_in,
                              void* d_out, int out_size, void* d_ws, size_t ws_size,
                              hipStream_t stream)
{
    const float* x    = (const float*)d_in[0];
    const float* ew1  = (const float*)d_in[1];
    const float* eb1  = (const float*)d_in[2];
    const float* eg1  = (const float*)d_in[3];
    const float* ebt1 = (const float*)d_in[4];
    const float* em1  = (const float*)d_in[5];
    const float* ev1  = (const float*)d_in[6];
    const float* ew2  = (const float*)d_in[7];
    const float* eb2  = (const float*)d_in[8];
    const float* eg2  = (const float*)d_in[9];
    const float* ebt2 = (const float*)d_in[10];
    const float* em2  = (const float*)d_in[11];
    const float* ev2  = (const float*)d_in[12];
    const float* ew3  = (const float*)d_in[13];
    const float* eb3  = (const float*)d_in[14];
    const float* cb   = (const float*)d_in[15];
    const float* dw1  = (const float*)d_in[16];
    const float* db1  = (const float*)d_in[17];
    const float* dg1  = (const float*)d_in[18];
    const float* dbt1 = (const float*)d_in[19];
    const float* dm1  = (const float*)d_in[20];
    const float* dv1  = (const float*)d_in[21];
    const float* dw2  = (const float*)d_in[22];
    const float* db2  = (const float*)d_in[23];
    const float* dg2  = (const float*)d_in[24];
    const float* dbt2 = (const float*)d_in[25];
    const float* dm2  = (const float*)d_in[26];
    const float* dv2  = (const float*)d_in[27];
    const float* dw3  = (const float*)d_in[28];
    const float* db3  = (const float*)d_in[29];

    float* outf = (float*)d_out;
    const size_t XR_OFF = 0;
    const size_t VQ_OFF = (size_t)B_ROWS * D_IN;
    const size_t IDX_OFF = VQ_OFF + 1;
    const size_t RE_OFF = IDX_OFF + B_ROWS;

    float* wsf = (float*)d_ws;
    size_t off = 0;
    float* buf256 = wsf + off; off += (size_t)B_ROWS * H1_N;
    float* buf128 = wsf + off; off += (size_t)B_ROWS * H2_N;
    float* zbuf   = wsf + off; off += (size_t)B_ROWS * LAT_N;
    float* zqbuf  = wsf + off; off += (size_t)B_ROWS * LAT_N;
    float* cnbuf  = wsf + off; off += K_CB;
    float* vqp    = wsf + off; off += 128;
    float* rep    = wsf + off; off += 1024;
    unsigned short* cbhi = (unsigned short*)(wsf + off); off += K_CB * LAT_N / 2;
    unsigned short* cblo = (unsigned short*)(wsf + off); off += K_CB * LAT_N / 2;
    float4* candb = (float4*)(wsf + off); off += (size_t)B_ROWS * 8 * 4;
    int* rcnt  = (int*)(wsf + off); off += 16;
    int* rlist = (int*)(wsf + off); off += B_ROWS;
    // decoder weights, k-major bf16 hi/lo
    unsigned short* w1hi = (unsigned short*)(wsf + off); off += (H2_N * LAT_N) / 2;
    unsigned short* w1lo = (unsigned short*)(wsf + off); off += (H2_N * LAT_N) / 2;
    unsigned short* w2hi = (unsigned short*)(wsf + off); off += (H1_N * H2_N) / 2;
    unsigned short* w2lo = (unsigned short*)(wsf + off); off += (H1_N * H2_N) / 2;
    unsigned short* w3hi = (unsigned short*)(wsf + off); off += (D_IN * H1_N) / 2;
    unsigned short* w3lo = (unsigned short*)(wsf + off); off += (D_IN * H1_N) / 2;

    dim3 blk(256);
    const int GX = B_ROWS / BM;   // 256
    const int GXM = B_ROWS / 128; // 256 (mfma row blocks)

    vq_prep<<<dim3(K_CB / 256), blk, 0, stream>>>(cb, cbhi, cblo, cnbuf, rcnt);
    wprep<<<dim3((LAT_N * H2_N + 255) / 256), blk, 0, stream>>>(dw1, w1hi, w1lo, LAT_N, H2_N);
    wprep<<<dim3((H2_N * H1_N + 255) / 256), blk, 0, stream>>>(dw2, w2hi, w2lo, H2_N, H1_N);
    wprep<<<dim3((H1_N * D_IN + 255) / 256), blk, 0, stream>>>(dw3, w3hi, w3lo, H1_N, D_IN);

    // encoder (exact f32: z_e feeds the argmin)
    gemm_fused<0><<<dim3(GX, H1_N / BN), blk, 0, stream>>>(
        x, ew1, eb1, eg1, ebt1, em1, ev1, buf256, nullptr, nullptr, D_IN, H1_N);
    gemm_fused<0><<<dim3(GX, 1), blk, 0, stream>>>(
        buf256, ew2, eb2, eg2, ebt2, em2, ev2, buf128, nullptr, nullptr, H1_N, H2_N);
    gemm_fused<1><<<dim3(GX, 1), blk, 0, stream>>>(
        buf128, ew3, eb3, nullptr, nullptr, nullptr, nullptr, zbuf, nullptr, nullptr,
        H2_N, LAT_N);

    // vector quantization: MFMA top-2 -> merge/flag -> exact repair -> gather
    vq_mfma<<<dim3(1024), blk, 0, stream>>>(zbuf, cbhi, cblo, cnbuf, candb);
    vq_merge<<<dim3(B_ROWS / 256), blk, 0, stream>>>(
        candb, outf + IDX_OFF, rlist, rcnt);
    vq_repair<<<dim3(128), blk, 0, stream>>>(
        rcnt, rlist, zbuf, cb, cnbuf, outf + IDX_OFF);
    vq_zqloss<<<dim3(B_ROWS / 256), blk, 0, stream>>>(
        outf + IDX_OFF, zbuf, cb, zqbuf, vqp);

    // decoder (bf16x3 MFMA)
    mfma_gemm<0, LAT_N><<<dim3(GXM, H2_N / 128), blk, 0, stream>>>(
        zqbuf, w1hi, w1lo, db1, dg1, dbt1, dm1, dv1, buf128, nullptr, nullptr, H2_N);
    mfma_gemm<0, H2_N><<<dim3(GXM, H1_N / 128), blk, 0, stream>>>(
        buf128, w2hi, w2lo, db2, dg2, dbt2, dm2, dv2, buf256, nullptr, nullptr, H1_N);
    mfma_gemm<2, H1_N><<<dim3(GXM, D_IN / 128), blk, 0, stream>>>(
        buf256, w3hi, w3lo, db3, nullptr, nullptr, nullptr, nullptr,
        outf + XR_OFF, x, rep, D_IN);

    finalize_kernel<<<dim3(1), blk, 0, stream>>>(
        vqp, 128, rep, 1024, outf + VQ_OFF, outf + RE_OFF);
}

// Round 6
// 417.854 us; speedup vs baseline: 1.3200x; 1.0519x over previous
//
#include <hip/hip_runtime.h>

#define B_ROWS 32768
#define D_IN   512
#define H1_N   256
#define H2_N   128
#define LAT_N  64
#define K_CB   2048

#define BM 64
#define BN 128
#define BK 32

#define VQ_MARGIN 4.0e-3f

typedef __attribute__((ext_vector_type(8))) short s8v;   // 8 bf16 (4 VGPRs)
typedef __attribute__((ext_vector_type(4))) float f4v;   // 4 f32 acc

__device__ inline unsigned short f2bf(float f) {
    union { float f; unsigned u; } v; v.f = f;
    unsigned r = v.u + 0x7fffu + ((v.u >> 16) & 1u);
    return (unsigned short)(r >> 16);
}
__device__ inline float bf2f(unsigned short h) {
    union { unsigned u; float f; } v; v.u = ((unsigned)h) << 16;
    return v.f;
}

// XOR swizzle for k-major LDS tiles (f32 GEMM path)
#define SWZ(row) ((((row) >> 2) & 7) << 3)

// ---------------- f32 GEMM (encoder only) ----------------
// BM=64 x BN=128 tile, 256 threads, acc 4x8/thread.
// MODE 0: out = BN(ReLU(A@W + bias));  MODE 1: out = A@W + bias
template <int MODE>
__global__ __launch_bounds__(256, 4) void gemm_fused(
    const float* __restrict__ A, const float* __restrict__ W,
    const float* __restrict__ bias,
    const float* __restrict__ bn_g, const float* __restrict__ bn_b,
    const float* __restrict__ bn_m, const float* __restrict__ bn_v,
    float* __restrict__ out, int M, int N)
{
    __shared__ float sA[BK][BM];
    __shared__ float sB[BK][BN];
    const int tid = threadIdx.x;
    const int tr = tid >> 4;   // 0..15 -> 4 rows each
    const int tc = tid & 15;   // 0..15 -> 8 cols each
    const int row0 = blockIdx.x * BM;
    const int n0   = blockIdx.y * BN;

    float acc[4][8];
#pragma unroll
    for (int i = 0; i < 4; ++i)
#pragma unroll
        for (int j = 0; j < 8; ++j) acc[i][j] = 0.f;

    for (int k0 = 0; k0 < M; k0 += BK) {
        // stage A tile [BM=64][BK=32] -> k-major sA[BK][BM] (swizzled)
#pragma unroll
        for (int it = 0; it < 2; ++it) {
            int s = tid + it * 256;         // 0..511
            int m = s >> 3;                 // 0..63
            int kq = s & 7;                 // 0..7
            float4 v = *reinterpret_cast<const float4*>(
                &A[(size_t)(row0 + m) * M + k0 + kq * 4]);
            int kk = kq * 4;
            sA[kk + 0][m ^ SWZ(kk + 0)] = v.x;
            sA[kk + 1][m ^ SWZ(kk + 1)] = v.y;
            sA[kk + 2][m ^ SWZ(kk + 2)] = v.z;
            sA[kk + 3][m ^ SWZ(kk + 3)] = v.w;
        }
        // stage W tile [BK][BN]
#pragma unroll
        for (int it = 0; it < 4; ++it) {
            int s = tid + it * 256;
            int k = s >> 5;                 // 0..31
            int nq = s & 31;                // 0..31
            int n = n0 + nq * 4;
            float4 v = make_float4(0.f, 0.f, 0.f, 0.f);
            if (n < N)
                v = *reinterpret_cast<const float4*>(&W[(size_t)(k0 + k) * N + n]);
            *reinterpret_cast<float4*>(&sB[k][nq * 4]) = v;
        }
        __syncthreads();
#pragma unroll 4
        for (int k = 0; k < BK; ++k) {
            int ac = (tr * 4) ^ SWZ(k);
            float4 a0 = *reinterpret_cast<float4*>(&sA[k][ac]);
            float4 b0 = *reinterpret_cast<float4*>(&sB[k][tc * 8]);
            float4 b1 = *reinterpret_cast<float4*>(&sB[k][tc * 8 + 4]);
            float a[4] = {a0.x, a0.y, a0.z, a0.w};
            float b[8] = {b0.x, b0.y, b0.z, b0.w, b1.x, b1.y, b1.z, b1.w};
#pragma unroll
            for (int i = 0; i < 4; ++i)
#pragma unroll
                for (int j = 0; j < 8; ++j)
                    acc[i][j] = fmaf(a[i], b[j], acc[i][j]);
        }
        __syncthreads();
    }

    const int nb = n0 + tc * 8;
    if (nb < N) {
        float bi[8], sc[8], sh[8];
#pragma unroll
        for (int j = 0; j < 8; ++j) {
            int n = nb + j;
            bi[j] = bias[n];
            if (MODE == 0) {
                float s = bn_g[n] * rsqrtf(bn_v[n] + 1e-5f);
                sc[j] = s;
                sh[j] = bn_b[n] - bn_m[n] * s;
            }
        }
#pragma unroll
        for (int i = 0; i < 4; ++i) {
            int row = row0 + tr * 4 + i;
            float o[8];
#pragma unroll
            for (int j = 0; j < 8; ++j) {
                float v = acc[i][j] + bi[j];
                if (MODE == 0) {
                    v = v > 0.f ? v : 0.f;
                    v = v * sc[j] + sh[j];
                }
                o[j] = v;
            }
            *reinterpret_cast<float4*>(&out[(size_t)row * N + nb]) =
                make_float4(o[0], o[1], o[2], o[3]);
            *reinterpret_cast<float4*>(&out[(size_t)row * N + nb + 4]) =
                make_float4(o[4], o[5], o[6], o[7]);
        }
    }
}

// ---------------- decoder weight prep: [K][N] f32 -> [N][K] bf16 hi/lo ----
__global__ __launch_bounds__(256) void wprep(
    const float* __restrict__ w, unsigned short* __restrict__ w_hi,
    unsigned short* __restrict__ w_lo, int K, int N)
{
    int idx = blockIdx.x * 256 + threadIdx.x;
    if (idx >= N * K) return;
    int n = idx / K, k = idx - n * K;
    float f = w[(size_t)k * N + n];
    unsigned u = __float_as_uint(f);
    float lo = f - __uint_as_float(u & 0xffff0000u);
    w_hi[idx] = (unsigned short)(u >> 16);
    w_lo[idx] = (unsigned short)(__float_as_uint(lo) >> 16);
}

// ---------------- MFMA decoder GEMM (bf16x3 split precision) ----------
// MODE 0: out = BN(ReLU(A@W+b));  MODE 2: out = A@W+b, + (out-x)^2 partials
template <int MODE, int K>
__global__ __launch_bounds__(256, 2) void mfma_gemm(
    const float* __restrict__ A,
    const unsigned short* __restrict__ w_hi,
    const unsigned short* __restrict__ w_lo,
    const float* __restrict__ bias,
    const float* __restrict__ bn_g, const float* __restrict__ bn_b,
    const float* __restrict__ bn_m, const float* __restrict__ bn_v,
    float* __restrict__ out,
    const float* __restrict__ xref, float* __restrict__ partials, int N)
{
    const int lane = threadIdx.x & 63;
    const int wv = threadIdx.x >> 6;          // 0..3
    const int wr = wv >> 1, wc = wv & 1;      // 2x2 waves over 128x128
    const int rbase = blockIdx.x * 128 + wr * 64;
    const int cbase = blockIdx.y * 128 + wc * 64;
    const int lr = lane & 15, lg = lane >> 4;

    f4v acc[4][4];
#pragma unroll
    for (int rt = 0; rt < 4; ++rt)
#pragma unroll
        for (int ct = 0; ct < 4; ++ct)
            acc[rt][ct] = (f4v){0.f, 0.f, 0.f, 0.f};

#pragma unroll
    for (int ks = 0; ks < K / 32; ++ks) {
        s8v ah[4], al[4], bh[4], bl[4];
#pragma unroll
        for (int rt = 0; rt < 4; ++rt) {
            const float* p =
                &A[(size_t)(rbase + rt * 16 + lr) * K + ks * 32 + lg * 8];
            float4 v0 = *reinterpret_cast<const float4*>(p);
            float4 v1 = *reinterpret_cast<const float4*>(p + 4);
            float fv[8] = {v0.x, v0.y, v0.z, v0.w, v1.x, v1.y, v1.z, v1.w};
            unsigned uu[8], ll[8];
#pragma unroll
            for (int j = 0; j < 8; ++j) {
                uu[j] = __float_as_uint(fv[j]);
                float lo = fv[j] - __uint_as_float(uu[j] & 0xffff0000u);
                ll[j] = __float_as_uint(lo);
            }
            union { s8v v; unsigned w[4]; } H, L;
#pragma unroll
            for (int m = 0; m < 4; ++m) {
                H.w[m] = __builtin_amdgcn_perm(uu[2 * m + 1], uu[2 * m], 0x07060302u);
                L.w[m] = __builtin_amdgcn_perm(ll[2 * m + 1], ll[2 * m], 0x07060302u);
            }
            ah[rt] = H.v;
            al[rt] = L.v;
        }
#pragma unroll
        for (int ct = 0; ct < 4; ++ct) {
            size_t off = (size_t)(cbase + ct * 16 + lr) * K + ks * 32 + lg * 8;
            bh[ct] = *reinterpret_cast<const s8v*>(&w_hi[off]);
            bl[ct] = *reinterpret_cast<const s8v*>(&w_lo[off]);
        }
#pragma unroll
        for (int rt = 0; rt < 4; ++rt)
#pragma unroll
            for (int ct = 0; ct < 4; ++ct) {
                acc[rt][ct] = __builtin_amdgcn_mfma_f32_16x16x32_bf16(
                    ah[rt], bh[ct], acc[rt][ct], 0, 0, 0);
                acc[rt][ct] = __builtin_amdgcn_mfma_f32_16x16x32_bf16(
                    al[rt], bh[ct], acc[rt][ct], 0, 0, 0);
                acc[rt][ct] = __builtin_amdgcn_mfma_f32_16x16x32_bf16(
                    ah[rt], bl[ct], acc[rt][ct], 0, 0, 0);
            }
    }

    float sq = 0.f;
#pragma unroll
    for (int ct = 0; ct < 4; ++ct) {
        int col = cbase + ct * 16 + lr;
        float bi = bias[col];
        float sc = 0.f, sh = 0.f;
        if (MODE == 0) {
            float s = bn_g[col] * rsqrtf(bn_v[col] + 1e-5f);
            sc = s;
            sh = bn_b[col] - bn_m[col] * s;
        }
#pragma unroll
        for (int rt = 0; rt < 4; ++rt)
#pragma unroll
            for (int i = 0; i < 4; ++i) {
                int row = rbase + rt * 16 + lg * 4 + i;
                float v = acc[rt][ct][i] + bi;
                if (MODE == 0) v = fmaxf(v, 0.f) * sc + sh;
                if (MODE == 2) {
                    float d = v - xref[(size_t)row * N + col];
                    sq = fmaf(d, d, sq);
                }
                out[(size_t)row * N + col] = v;
            }
    }
    if (MODE == 2) {
        __shared__ float red[256];
        red[threadIdx.x] = sq;
        __syncthreads();
        for (int off = 128; off > 0; off >>= 1) {
            if (threadIdx.x < off) red[threadIdx.x] += red[threadIdx.x + off];
            __syncthreads();
        }
        if (threadIdx.x == 0)
            partials[blockIdx.y * gridDim.x + blockIdx.x] = red[0];
    }
}

// codebook -> bf16 hi/lo split + squared norms; also zero repair counter
__global__ __launch_bounds__(256) void vq_prep(
    const float* __restrict__ cb, unsigned short* __restrict__ cb_hi,
    unsigned short* __restrict__ cb_lo, float* __restrict__ cn,
    int* __restrict__ rcnt)
{
    if (blockIdx.x == 0 && threadIdx.x == 0) rcnt[0] = 0;
    int j = blockIdx.x * 256 + threadIdx.x;   // 0..2047
    float s = 0.f;
#pragma unroll
    for (int lq = 0; lq < 16; ++lq) {
        float4 v = *reinterpret_cast<const float4*>(&cb[(size_t)j * LAT_N + lq * 4]);
        float e[4] = {v.x, v.y, v.z, v.w};
        ushort4 h, l;
        unsigned short* hp = &h.x;
        unsigned short* lp = &l.x;
#pragma unroll
        for (int t = 0; t < 4; ++t) {
            s = fmaf(e[t], e[t], s);
            unsigned short hb = f2bf(e[t]);
            hp[t] = hb;
            lp[t] = f2bf(e[t] - bf2f(hb));
        }
        *reinterpret_cast<ushort4*>(&cb_hi[(size_t)j * LAT_N + lq * 4]) = h;
        *reinterpret_cast<ushort4*>(&cb_lo[(size_t)j * LAT_N + lq * 4]) = l;
    }
    cn[j] = s;
}

// VQ scores via bf16x3 MFMA with top-2 tracking.
__global__ __launch_bounds__(256) void vq_mfma(
    const float* __restrict__ z, const unsigned short* __restrict__ cb_hi,
    const unsigned short* __restrict__ cb_lo, const float* __restrict__ cnorm,
    float4* __restrict__ cand)
{
    const int lane = threadIdx.x & 63;
    const int wid  = blockIdx.x * 4 + (threadIdx.x >> 6);
    const int rbase = (wid >> 3) * 64;
    const int cblk  = wid & 7;
    const int cbase = cblk * 256;
    const int lr = lane & 15;
    const int lg = lane >> 4;

    s8v a_hi[4][2], a_lo[4][2];
#pragma unroll
    for (int rt = 0; rt < 4; ++rt) {
        int row = rbase + rt * 16 + lr;
#pragma unroll
        for (int ks = 0; ks < 2; ++ks) {
            const float* p = &z[(size_t)row * LAT_N + ks * 32 + lg * 8];
            float4 v0 = *reinterpret_cast<const float4*>(p);
            float4 v1 = *reinterpret_cast<const float4*>(p + 4);
            float vv[8] = {v0.x, v0.y, v0.z, v0.w, v1.x, v1.y, v1.z, v1.w};
#pragma unroll
            for (int jj = 0; jj < 8; ++jj) {
                unsigned short hb = f2bf(vv[jj]);
                a_hi[rt][ks][jj] = (short)hb;
                a_lo[rt][ks][jj] = (short)f2bf(vv[jj] - bf2f(hb));
            }
        }
    }

    float b1[4][4], b2[4][4];
    int j1[4][4];
#pragma unroll
    for (int rt = 0; rt < 4; ++rt)
#pragma unroll
        for (int i = 0; i < 4; ++i) {
            b1[rt][i] = 3.4e38f; b2[rt][i] = 3.4e38f; j1[rt][i] = 0;
        }

    for (int ct = 0; ct < 16; ++ct) {
        int col = cbase + ct * 16 + lr;
        const unsigned short* ph = &cb_hi[(size_t)col * LAT_N + lg * 8];
        const unsigned short* pl = &cb_lo[(size_t)col * LAT_N + lg * 8];
        s8v bh0 = *reinterpret_cast<const s8v*>(ph);
        s8v bh1 = *reinterpret_cast<const s8v*>(ph + 32);
        s8v bl0 = *reinterpret_cast<const s8v*>(pl);
        s8v bl1 = *reinterpret_cast<const s8v*>(pl + 32);
        float cn = cnorm[col];
#pragma unroll
        for (int rt = 0; rt < 4; ++rt) {
            f4v acc = {0.f, 0.f, 0.f, 0.f};
            acc = __builtin_amdgcn_mfma_f32_16x16x32_bf16(a_hi[rt][0], bh0, acc, 0, 0, 0);
            acc = __builtin_amdgcn_mfma_f32_16x16x32_bf16(a_hi[rt][1], bh1, acc, 0, 0, 0);
            acc = __builtin_amdgcn_mfma_f32_16x16x32_bf16(a_lo[rt][0], bh0, acc, 0, 0, 0);
            acc = __builtin_amdgcn_mfma_f32_16x16x32_bf16(a_lo[rt][1], bh1, acc, 0, 0, 0);
            acc = __builtin_amdgcn_mfma_f32_16x16x32_bf16(a_hi[rt][0], bl0, acc, 0, 0, 0);
            acc = __builtin_amdgcn_mfma_f32_16x16x32_bf16(a_hi[rt][1], bl1, acc, 0, 0, 0);
#pragma unroll
            for (int i = 0; i < 4; ++i) {
                float d = fmaf(-2.f, acc[i], cn);
                if (d < b1[rt][i]) {
                    b2[rt][i] = b1[rt][i];
                    b1[rt][i] = d;
                    j1[rt][i] = col;
                } else if (d < b2[rt][i]) {
                    b2[rt][i] = d;
                }
            }
        }
    }

#pragma unroll
    for (int off = 1; off < 16; off <<= 1) {
#pragma unroll
        for (int rt = 0; rt < 4; ++rt)
#pragma unroll
            for (int i = 0; i < 4; ++i) {
                float o1 = __shfl_xor(b1[rt][i], off);
                float o2 = __shfl_xor(b2[rt][i], off);
                int oj = __shfl_xor(j1[rt][i], off);
                float nb2 = fminf(fmaxf(b1[rt][i], o1), fminf(b2[rt][i], o2));
                if (o1 < b1[rt][i] ||
                    (o1 == b1[rt][i] && oj < j1[rt][i])) {
                    b1[rt][i] = o1;
                    j1[rt][i] = oj;
                }
                b2[rt][i] = nb2;
            }
    }
    if (lr == 0) {
#pragma unroll
        for (int rt = 0; rt < 4; ++rt)
#pragma unroll
            for (int i = 0; i < 4; ++i) {
                int row = rbase + rt * 16 + lg * 4 + i;
                cand[(size_t)row * 8 + cblk] = make_float4(
                    b1[rt][i], __int_as_float(j1[rt][i]), b2[rt][i], 0.f);
            }
    }
}

// merge 8 col-block candidates/row; flag near-ties for exact repair
__global__ __launch_bounds__(256) void vq_merge(
    const float4* __restrict__ cand, float* __restrict__ idxf,
    int* __restrict__ rlist, int* __restrict__ rcnt)
{
    int row = blockIdx.x * 256 + threadIdx.x;
    const float4* c = &cand[(size_t)row * 8];
    float4 c0 = c[0];
    float b1 = c0.x, b2 = c0.z;
    int j1 = __float_as_int(c0.y);
#pragma unroll
    for (int t = 1; t < 8; ++t) {
        float4 ct = c[t];
        float o1 = ct.x, o2 = ct.z;
        int oj = __float_as_int(ct.y);
        float nb2 = fminf(fmaxf(b1, o1), fminf(b2, o2));
        if (o1 < b1 || (o1 == b1 && oj < j1)) { b1 = o1; j1 = oj; }
        b2 = nb2;
    }
    idxf[row] = (float)j1;
    if (!(b2 - b1 >= VQ_MARGIN)) {
        int s = atomicAdd(rcnt, 1);
        if (s < B_ROWS) rlist[s] = row;
    }
}

// exact-f32 full-row rescan of flagged rows (register-light)
#define RB 8
__global__ __launch_bounds__(256) void vq_repair(
    const int* __restrict__ rcnt, const int* __restrict__ rlist,
    const float* __restrict__ z, const float* __restrict__ cb,
    const float* __restrict__ cn, float* __restrict__ idxf)
{
    __shared__ float sz[RB][LAT_N];
    __shared__ float rv[256];
    __shared__ int ri[256];
    const int tid = threadIdx.x;
    const int count = min(rcnt[0], B_ROWS);
    if (blockIdx.x * RB >= count) return;
    for (int base = blockIdx.x * RB; base < count; base += gridDim.x * RB) {
        int nr = min(RB, count - base);
        __syncthreads();
        for (int s = tid; s < nr * LAT_N; s += 256) {
            int r = s >> 6, d = s & 63;
            int rr = rlist[base + r];
            rr = ((unsigned)rr < (unsigned)B_ROWS) ? rr : 0;
            sz[r][d] = z[(size_t)rr * LAT_N + d];
        }
        __syncthreads();
        float bv[RB];
        int bj[RB];
#pragma unroll
        for (int r = 0; r < RB; ++r) { bv[r] = 3.4e38f; bj[r] = 0; }
        for (int k = 0; k < K_CB / 256; ++k) {
            int cidx = tid + k * 256;
            float acc[RB];
#pragma unroll
            for (int r = 0; r < RB; ++r) acc[r] = 0.f;
            const float* cp = &cb[(size_t)cidx * LAT_N];
#pragma unroll 2
            for (int d4 = 0; d4 < 16; ++d4) {
                float4 cv = *reinterpret_cast<const float4*>(cp + d4 * 4);
#pragma unroll
                for (int r = 0; r < RB; ++r) {
                    acc[r] = fmaf(sz[r][d4 * 4 + 0], cv.x, acc[r]);
                    acc[r] = fmaf(sz[r][d4 * 4 + 1], cv.y, acc[r]);
                    acc[r] = fmaf(sz[r][d4 * 4 + 2], cv.z, acc[r]);
                    acc[r] = fmaf(sz[r][d4 * 4 + 3], cv.w, acc[r]);
                }
            }
            float cnv = cn[cidx];
#pragma unroll
            for (int r = 0; r < RB; ++r) {
                float d = fmaf(-2.f, acc[r], cnv);
                if (d < bv[r] || (d == bv[r] && cidx < bj[r])) {
                    bv[r] = d; bj[r] = cidx;
                }
            }
        }
        for (int r = 0; r < RB; ++r) {
            if (r >= nr) break;
            rv[tid] = bv[r];
            ri[tid] = bj[r];
            __syncthreads();
            for (int off = 128; off > 0; off >>= 1) {
                if (tid < off) {
                    float ov = rv[tid + off];
                    int oi = ri[tid + off];
                    if (ov < rv[tid] || (ov == rv[tid] && oi < ri[tid])) {
                        rv[tid] = ov; ri[tid] = oi;
                    }
                }
                __syncthreads();
            }
            if (tid == 0) {
                int rr = rlist[base + r];
                if ((unsigned)rr < (unsigned)B_ROWS)
                    idxf[rr] = (float)ri[0];
            }
            __syncthreads();
        }
    }
}

// gather z_q from final idx + vq-loss partials
__global__ __launch_bounds__(256) void vq_zqloss(
    const float* __restrict__ idxf, const float* __restrict__ z,
    const float* __restrict__ cb, float* __restrict__ zq,
    float* __restrict__ partials)
{
    __shared__ float red[256];
    int tid = threadIdx.x;
    int row = blockIdx.x * 256 + tid;
    int bj = (int)idxf[row];
    bj = ((unsigned)bj < (unsigned)K_CB) ? bj : 0;
    float sq = 0.f;
#pragma unroll
    for (int lq = 0; lq < 16; ++lq) {
        float4 cv = *reinterpret_cast<const float4*>(&cb[(size_t)bj * LAT_N + lq * 4]);
        float4 zv = *reinterpret_cast<const float4*>(&z[(size_t)row * LAT_N + lq * 4]);
        *reinterpret_cast<float4*>(&zq[(size_t)row * LAT_N + lq * 4]) = cv;
        float d0 = cv.x - zv.x, d1 = cv.y - zv.y;
        float d2 = cv.z - zv.z, d3 = cv.w - zv.w;
        sq = fmaf(d0, d0, sq); sq = fmaf(d1, d1, sq);
        sq = fmaf(d2, d2, sq); sq = fmaf(d3, d3, sq);
    }
    red[tid] = sq;
    __syncthreads();
    for (int off = 128; off > 0; off >>= 1) {
        if (tid < off) red[tid] += red[tid + off];
        __syncthreads();
    }
    if (tid == 0) partials[blockIdx.x] = red[0];
}

__global__ __launch_bounds__(256) void finalize_kernel(
    const float* __restrict__ vqp, int nvq,
    const float* __restrict__ rep, int nre,
    float* __restrict__ vq_out, float* __restrict__ re_out)
{
    __shared__ float s[256];
    int tid = threadIdx.x;
    float a = 0.f;
    for (int i = tid; i < nvq; i += 256) a += vqp[i];
    s[tid] = a;
    __syncthreads();
    for (int off = 128; off > 0; off >>= 1) {
        if (tid < off) s[tid] += s[tid + off];
        __syncthreads();
    }
    if (tid == 0) *vq_out = 1.25f * s[0] / (float)(B_ROWS * LAT_N);
    __syncthreads();
    float b = 0.f;
    for (int i = tid; i < nre; i += 256) b += rep[i];
    s[tid] = b;
    __syncthreads();
    for (int off = 128; off > 0; off >>= 1) {
        if (tid < off) s[tid] += s[tid + off];
        __syncthreads();
    }
    if (tid == 0) *re_out = s[0] / (float)(B_ROWS * D_IN);
}

extern "C" void kernel_launch(void* const* d_in, const int* in_sizes, int n_in,
                              void* d_out, int out_size, void* d_ws, size_t ws_size,
                              hipStream_t stream)
{
    const float* x    = (const float*)d_in[0];
    const float* ew1  = (const float*)d_in[1];
    const float* eb1  = (const float*)d_in[2];
    const float* eg1  = (const float*)d_in[3];
    const float* ebt1 = (const float*)d_in[4];
    const float* em1  = (const float*)d_in[5];
    const float* ev1  = (const float*)d_in[6];
    const float* ew2  = (const float*)d_in[7];
    const float* eb2  = (const float*)d_in[8];
    const float* eg2  = (const float*)d_in[9];
    const float* ebt2 = (const float*)d_in[10];
    const float* em2  = (const float*)d_in[11];
    const float* ev2  = (const float*)d_in[12];
    const float* ew3  = (const float*)d_in[13];
    const float* eb3  = (const float*)d_in[14];
    const float* cb   = (const float*)d_in[15];
    const float* dw1  = (const float*)d_in[16];
    const float* db1  = (const float*)d_in[17];
    const float* dg1  = (const float*)d_in[18];
    const float* dbt1 = (const float*)d_in[19];
    const float* dm1  = (const float*)d_in[20];
    const float* dv1  = (const float*)d_in[21];
    const float* dw2  = (const float*)d_in[22];
    const float* db2  = (const float*)d_in[23];
    const float* dg2  = (const float*)d_in[24];
    const float* dbt2 = (const float*)d_in[25];
    const float* dm2  = (const float*)d_in[26];
    const float* dv2  = (const float*)d_in[27];
    const float* dw3  = (const float*)d_in[28];
    const float* db3  = (const float*)d_in[29];

    float* outf = (float*)d_out;
    const size_t XR_OFF = 0;
    const size_t VQ_OFF = (size_t)B_ROWS * D_IN;
    const size_t IDX_OFF = VQ_OFF + 1;
    const size_t RE_OFF = IDX_OFF + B_ROWS;

    float* wsf = (float*)d_ws;
    size_t off = 0;
    float* buf256 = wsf + off; off += (size_t)B_ROWS * H1_N;
    float* buf128 = wsf + off; off += (size_t)B_ROWS * H2_N;
    float* zbuf   = wsf + off; off += (size_t)B_ROWS * LAT_N;
    float* zqbuf  = wsf + off; off += (size_t)B_ROWS * LAT_N;
    float* cnbuf  = wsf + off; off += K_CB;
    float* vqp    = wsf + off; off += 128;
    float* rep    = wsf + off; off += 1024;
    unsigned short* cbhi = (unsigned short*)(wsf + off); off += K_CB * LAT_N / 2;
    unsigned short* cblo = (unsigned short*)(wsf + off); off += K_CB * LAT_N / 2;
    float4* candb = (float4*)(wsf + off); off += (size_t)B_ROWS * 8 * 4;
    int* rcnt  = (int*)(wsf + off); off += 16;
    int* rlist = (int*)(wsf + off); off += B_ROWS;
    // decoder weights, k-major bf16 hi/lo
    unsigned short* w1hi = (unsigned short*)(wsf + off); off += (H2_N * LAT_N) / 2;
    unsigned short* w1lo = (unsigned short*)(wsf + off); off += (H2_N * LAT_N) / 2;
    unsigned short* w2hi = (unsigned short*)(wsf + off); off += (H1_N * H2_N) / 2;
    unsigned short* w2lo = (unsigned short*)(wsf + off); off += (H1_N * H2_N) / 2;
    unsigned short* w3hi = (unsigned short*)(wsf + off); off += (D_IN * H1_N) / 2;
    unsigned short* w3lo = (unsigned short*)(wsf + off); off += (D_IN * H1_N) / 2;

    dim3 blk(256);
    const int GX = B_ROWS / BM;   // 512 (f32 row blocks)
    const int GXM = B_ROWS / 128; // 256 (mfma row blocks)

    vq_prep<<<dim3(K_CB / 256), blk, 0, stream>>>(cb, cbhi, cblo, cnbuf, rcnt);
    wprep<<<dim3((LAT_N * H2_N + 255) / 256), blk, 0, stream>>>(dw1, w1hi, w1lo, LAT_N, H2_N);
    wprep<<<dim3((H2_N * H1_N + 255) / 256), blk, 0, stream>>>(dw2, w2hi, w2lo, H2_N, H1_N);
    wprep<<<dim3((H1_N * D_IN + 255) / 256), blk, 0, stream>>>(dw3, w3hi, w3lo, H1_N, D_IN);

    // encoder (exact f32: z_e feeds the argmin)
    gemm_fused<0><<<dim3(GX, H1_N / BN), blk, 0, stream>>>(
        x, ew1, eb1, eg1, ebt1, em1, ev1, buf256, D_IN, H1_N);
    gemm_fused<0><<<dim3(GX, 1), blk, 0, stream>>>(
        buf256, ew2, eb2, eg2, ebt2, em2, ev2, buf128, H1_N, H2_N);
    gemm_fused<1><<<dim3(GX, 1), blk, 0, stream>>>(
        buf128, ew3, eb3, nullptr, nullptr, nullptr, nullptr, zbuf, H2_N, LAT_N);

    // vector quantization: MFMA top-2 -> merge/flag -> exact repair -> gather
    vq_mfma<<<dim3(1024), blk, 0, stream>>>(zbuf, cbhi, cblo, cnbuf, candb);
    vq_merge<<<dim3(B_ROWS / 256), blk, 0, stream>>>(
        candb, outf + IDX_OFF, rlist, rcnt);
    vq_repair<<<dim3(256), blk, 0, stream>>>(
        rcnt, rlist, zbuf, cb, cnbuf, outf + IDX_OFF);
    vq_zqloss<<<dim3(B_ROWS / 256), blk, 0, stream>>>(
        outf + IDX_OFF, zbuf, cb, zqbuf, vqp);

    // decoder (bf16x3 MFMA)
    mfma_gemm<0, LAT_N><<<dim3(GXM, H2_N / 128), blk, 0, stream>>>(
        zqbuf, w1hi, w1lo, db1, dg1, dbt1, dm1, dv1, buf128, nullptr, nullptr, H2_N);
    mfma_gemm<0, H2_N><<<dim3(GXM, H1_N / 128), blk, 0, stream>>>(
        buf128, w2hi, w2lo, db2, dg2, dbt2, dm2, dv2, buf256, nullptr, nullptr, H1_N);
    mfma_gemm<2, H1_N><<<dim3(GXM, D_IN / 128), blk, 0, stream>>>(
        buf256, w3hi, w3lo, db3, nullptr, nullptr, nullptr, nullptr,
        outf + XR_OFF, x, rep, D_IN);

    finalize_kernel<<<dim3(1), blk, 0, stream>>>(
        vqp, 128, rep, 1024, outf + VQ_OFF, outf + RE_OFF);
}

// Round 7
// 417.782 us; speedup vs baseline: 1.3202x; 1.0002x over previous
//
#include <hip/hip_runtime.h>

#define B_ROWS 32768
#define D_IN   512
#define H1_N   256
#define H2_N   128
#define LAT_N  64
#define K_CB   2048

#define BN 128
#define BK 32

#define VQ_MARGIN 4.0e-3f

typedef __attribute__((ext_vector_type(8))) short s8v;   // 8 bf16 (4 VGPRs)
typedef __attribute__((ext_vector_type(4))) float f4v;   // 4 f32 acc

__device__ inline unsigned short f2bf(float f) {
    union { float f; unsigned u; } v; v.f = f;
    unsigned r = v.u + 0x7fffu + ((v.u >> 16) & 1u);
    return (unsigned short)(r >> 16);
}
__device__ inline float bf2f(unsigned short h) {
    union { unsigned u; float f; } v; v.u = ((unsigned)h) << 16;
    return v.f;
}

// XOR swizzle for k-major LDS A-tiles (f32 GEMM path)
#define SWZ(row) ((((row) >> 2) & 7) << 3)

// ---------------- f32 GEMM (encoder only) ----------------
// BMT x 128 tile, 256 threads, microtile (BMT/16) x 8 with column-split
// (cols tc*4..+3 and 64+tc*4..+3) so sB reads are conflict-free.
// MODE 0: out = BN(ReLU(A@W + bias));  MODE 1: out = A@W + bias
template <int MODE, int BMT>
__global__ __launch_bounds__(256, (BMT == 128) ? 2 : 6) void gemm_fused(
    const float* __restrict__ A, const float* __restrict__ W,
    const float* __restrict__ bias,
    const float* __restrict__ bn_g, const float* __restrict__ bn_b,
    const float* __restrict__ bn_m, const float* __restrict__ bn_v,
    float* __restrict__ out, int M, int N)
{
    constexpr int MR = BMT / 16;    // rows per thread: 8 or 4
    __shared__ float sA[BK][BMT];
    __shared__ float sB[BK][BN];
    const int tid = threadIdx.x;
    const int tr = tid >> 4;   // 0..15
    const int tc = tid & 15;   // 0..15
    const int row0 = blockIdx.x * BMT;
    const int n0   = blockIdx.y * BN;

    float acc[MR][8];
#pragma unroll
    for (int i = 0; i < MR; ++i)
#pragma unroll
        for (int j = 0; j < 8; ++j) acc[i][j] = 0.f;

    for (int k0 = 0; k0 < M; k0 += BK) {
        // stage A tile [BMT][BK] -> k-major sA[BK][BMT] (transposed, swizzled)
#pragma unroll
        for (int it = 0; it < BMT / 32; ++it) {
            int s = tid + it * 256;
            int m = s >> 3;
            int kq = s & 7;
            float4 v = *reinterpret_cast<const float4*>(
                &A[(size_t)(row0 + m) * M + k0 + kq * 4]);
            int kk = kq * 4;
            sA[kk + 0][m ^ SWZ(kk + 0)] = v.x;
            sA[kk + 1][m ^ SWZ(kk + 1)] = v.y;
            sA[kk + 2][m ^ SWZ(kk + 2)] = v.z;
            sA[kk + 3][m ^ SWZ(kk + 3)] = v.w;
        }
        // stage W tile [BK][BN] (linear)
#pragma unroll
        for (int it = 0; it < 4; ++it) {
            int s = tid + it * 256;
            int k = s >> 5;
            int nq = s & 31;
            int n = n0 + nq * 4;
            float4 v = make_float4(0.f, 0.f, 0.f, 0.f);
            if (n < N)
                v = *reinterpret_cast<const float4*>(&W[(size_t)(k0 + k) * N + n]);
            *reinterpret_cast<float4*>(&sB[k][nq * 4]) = v;
        }
        __syncthreads();
#pragma unroll 4
        for (int k = 0; k < BK; ++k) {
            int ac = (tr * MR) ^ SWZ(k);
            float a[MR];
            {
                float4 a0 = *reinterpret_cast<float4*>(&sA[k][ac]);
                a[0] = a0.x; a[1] = a0.y; a[2] = a0.z; a[3] = a0.w;
                if constexpr (MR == 8) {
                    float4 a1 = *reinterpret_cast<float4*>(&sA[k][ac + 4]);
                    a[4] = a1.x; a[5] = a1.y; a[6] = a1.z; a[7] = a1.w;
                }
            }
            // conflict-free: 16 lanes read 256B consecutive per group
            float4 b0 = *reinterpret_cast<float4*>(&sB[k][tc * 4]);
            float4 b1 = *reinterpret_cast<float4*>(&sB[k][64 + tc * 4]);
            float b[8] = {b0.x, b0.y, b0.z, b0.w, b1.x, b1.y, b1.z, b1.w};
#pragma unroll
            for (int i = 0; i < MR; ++i)
#pragma unroll
                for (int j = 0; j < 8; ++j)
                    acc[i][j] = fmaf(a[i], b[j], acc[i][j]);
        }
        __syncthreads();
    }

    const int nb0 = n0 + tc * 4;
    const int nb1 = n0 + 64 + tc * 4;
    float bi[8], sc[8], sh[8];
#pragma unroll
    for (int g = 0; g < 2; ++g) {
        int nb = g ? nb1 : nb0;
        if (nb < N) {
#pragma unroll
            for (int j = 0; j < 4; ++j) {
                int n = nb + j;
                bi[g * 4 + j] = bias[n];
                if (MODE == 0) {
                    float s = bn_g[n] * rsqrtf(bn_v[n] + 1e-5f);
                    sc[g * 4 + j] = s;
                    sh[g * 4 + j] = bn_b[n] - bn_m[n] * s;
                }
            }
        }
    }
#pragma unroll
    for (int i = 0; i < MR; ++i) {
        int row = row0 + tr * MR + i;
#pragma unroll
        for (int g = 0; g < 2; ++g) {
            int nb = g ? nb1 : nb0;
            if (nb < N) {
                float o[4];
#pragma unroll
                for (int j = 0; j < 4; ++j) {
                    float v = acc[i][g * 4 + j] + bi[g * 4 + j];
                    if (MODE == 0) {
                        v = v > 0.f ? v : 0.f;
                        v = v * sc[g * 4 + j] + sh[g * 4 + j];
                    }
                    o[j] = v;
                }
                *reinterpret_cast<float4*>(&out[(size_t)row * N + nb]) =
                    make_float4(o[0], o[1], o[2], o[3]);
            }
        }
    }
}

// ---------------- decoder weight prep: [K][N] f32 -> [N][K] bf16 hi/lo ----
__global__ __launch_bounds__(256) void wprep(
    const float* __restrict__ w, unsigned short* __restrict__ w_hi,
    unsigned short* __restrict__ w_lo, int K, int N)
{
    int idx = blockIdx.x * 256 + threadIdx.x;
    if (idx >= N * K) return;
    int n = idx / K, k = idx - n * K;
    float f = w[(size_t)k * N + n];
    unsigned u = __float_as_uint(f);
    float lo = f - __uint_as_float(u & 0xffff0000u);
    w_hi[idx] = (unsigned short)(u >> 16);
    w_lo[idx] = f2bf(lo);
}

// ---------------- MFMA decoder GEMM, pre-split bf16 hi/lo activations ----
// MODE 0: v = BN(ReLU(A@W+b)) -> out_hi/out_lo (bf16 split for next layer)
// MODE 2: v = A@W+b -> out_f32, + (v-xref)^2 partials
template <int MODE, int K>
__global__ __launch_bounds__(256, 2) void mfma_gemm(
    const unsigned short* __restrict__ A_hi,
    const unsigned short* __restrict__ A_lo,
    const unsigned short* __restrict__ w_hi,
    const unsigned short* __restrict__ w_lo,
    const float* __restrict__ bias,
    const float* __restrict__ bn_g, const float* __restrict__ bn_b,
    const float* __restrict__ bn_m, const float* __restrict__ bn_v,
    unsigned short* __restrict__ out_hi, unsigned short* __restrict__ out_lo,
    float* __restrict__ out_f32,
    const float* __restrict__ xref, float* __restrict__ partials, int N)
{
    const int lane = threadIdx.x & 63;
    const int wv = threadIdx.x >> 6;          // 0..3
    const int wr = wv >> 1, wc = wv & 1;      // 2x2 waves over 128x128
    const int rbase = blockIdx.x * 128 + wr * 64;
    const int cbase = blockIdx.y * 128 + wc * 64;
    const int lr = lane & 15, lg = lane >> 4;

    f4v acc[4][4];
#pragma unroll
    for (int rt = 0; rt < 4; ++rt)
#pragma unroll
        for (int ct = 0; ct < 4; ++ct)
            acc[rt][ct] = (f4v){0.f, 0.f, 0.f, 0.f};

#pragma unroll
    for (int ks = 0; ks < K / 32; ++ks) {
        s8v ah[4], al[4], bh[4], bl[4];
#pragma unroll
        for (int rt = 0; rt < 4; ++rt) {
            size_t off = (size_t)(rbase + rt * 16 + lr) * K + ks * 32 + lg * 8;
            ah[rt] = *reinterpret_cast<const s8v*>(&A_hi[off]);
            al[rt] = *reinterpret_cast<const s8v*>(&A_lo[off]);
        }
#pragma unroll
        for (int ct = 0; ct < 4; ++ct) {
            size_t off = (size_t)(cbase + ct * 16 + lr) * K + ks * 32 + lg * 8;
            bh[ct] = *reinterpret_cast<const s8v*>(&w_hi[off]);
            bl[ct] = *reinterpret_cast<const s8v*>(&w_lo[off]);
        }
#pragma unroll
        for (int rt = 0; rt < 4; ++rt)
#pragma unroll
            for (int ct = 0; ct < 4; ++ct) {
                acc[rt][ct] = __builtin_amdgcn_mfma_f32_16x16x32_bf16(
                    ah[rt], bh[ct], acc[rt][ct], 0, 0, 0);
                acc[rt][ct] = __builtin_amdgcn_mfma_f32_16x16x32_bf16(
                    al[rt], bh[ct], acc[rt][ct], 0, 0, 0);
                acc[rt][ct] = __builtin_amdgcn_mfma_f32_16x16x32_bf16(
                    ah[rt], bl[ct], acc[rt][ct], 0, 0, 0);
            }
    }

    float sq = 0.f;
#pragma unroll
    for (int ct = 0; ct < 4; ++ct) {
        int col = cbase + ct * 16 + lr;
        float bi = bias[col];
        float sc = 0.f, sh = 0.f;
        if (MODE == 0) {
            float s = bn_g[col] * rsqrtf(bn_v[col] + 1e-5f);
            sc = s;
            sh = bn_b[col] - bn_m[col] * s;
        }
#pragma unroll
        for (int rt = 0; rt < 4; ++rt)
#pragma unroll
            for (int i = 0; i < 4; ++i) {
                int row = rbase + rt * 16 + lg * 4 + i;
                float v = acc[rt][ct][i] + bi;
                if (MODE == 0) {
                    v = fmaxf(v, 0.f) * sc + sh;
                    unsigned u = __float_as_uint(v);
                    out_hi[(size_t)row * N + col] = (unsigned short)(u >> 16);
                    out_lo[(size_t)row * N + col] =
                        f2bf(v - __uint_as_float(u & 0xffff0000u));
                }
                if (MODE == 2) {
                    float d = v - xref[(size_t)row * N + col];
                    sq = fmaf(d, d, sq);
                    out_f32[(size_t)row * N + col] = v;
                }
            }
    }
    if (MODE == 2) {
        __shared__ float red[256];
        red[threadIdx.x] = sq;
        __syncthreads();
        for (int off = 128; off > 0; off >>= 1) {
            if (threadIdx.x < off) red[threadIdx.x] += red[threadIdx.x + off];
            __syncthreads();
        }
        if (threadIdx.x == 0)
            partials[blockIdx.y * gridDim.x + blockIdx.x] = red[0];
    }
}

// codebook -> bf16 hi/lo split + squared norms; also zero repair counter
__global__ __launch_bounds__(256) void vq_prep(
    const float* __restrict__ cb, unsigned short* __restrict__ cb_hi,
    unsigned short* __restrict__ cb_lo, float* __restrict__ cn,
    int* __restrict__ rcnt)
{
    if (blockIdx.x == 0 && threadIdx.x == 0) rcnt[0] = 0;
    int j = blockIdx.x * 256 + threadIdx.x;   // 0..2047
    float s = 0.f;
#pragma unroll
    for (int lq = 0; lq < 16; ++lq) {
        float4 v = *reinterpret_cast<const float4*>(&cb[(size_t)j * LAT_N + lq * 4]);
        float e[4] = {v.x, v.y, v.z, v.w};
        ushort4 h, l;
        unsigned short* hp = &h.x;
        unsigned short* lp = &l.x;
#pragma unroll
        for (int t = 0; t < 4; ++t) {
            s = fmaf(e[t], e[t], s);
            unsigned short hb = f2bf(e[t]);
            hp[t] = hb;
            lp[t] = f2bf(e[t] - bf2f(hb));
        }
        *reinterpret_cast<ushort4*>(&cb_hi[(size_t)j * LAT_N + lq * 4]) = h;
        *reinterpret_cast<ushort4*>(&cb_lo[(size_t)j * LAT_N + lq * 4]) = l;
    }
    cn[j] = s;
}

// VQ scores via bf16x3 MFMA with top-2 tracking.
__global__ __launch_bounds__(256) void vq_mfma(
    const float* __restrict__ z, const unsigned short* __restrict__ cb_hi,
    const unsigned short* __restrict__ cb_lo, const float* __restrict__ cnorm,
    float4* __restrict__ cand)
{
    const int lane = threadIdx.x & 63;
    const int wid  = blockIdx.x * 4 + (threadIdx.x >> 6);
    const int rbase = (wid >> 3) * 64;
    const int cblk  = wid & 7;
    const int cbase = cblk * 256;
    const int lr = lane & 15;
    const int lg = lane >> 4;

    s8v a_hi[4][2], a_lo[4][2];
#pragma unroll
    for (int rt = 0; rt < 4; ++rt) {
        int row = rbase + rt * 16 + lr;
#pragma unroll
        for (int ks = 0; ks < 2; ++ks) {
            const float* p = &z[(size_t)row * LAT_N + ks * 32 + lg * 8];
            float4 v0 = *reinterpret_cast<const float4*>(p);
            float4 v1 = *reinterpret_cast<const float4*>(p + 4);
            float vv[8] = {v0.x, v0.y, v0.z, v0.w, v1.x, v1.y, v1.z, v1.w};
#pragma unroll
            for (int jj = 0; jj < 8; ++jj) {
                unsigned short hb = f2bf(vv[jj]);
                a_hi[rt][ks][jj] = (short)hb;
                a_lo[rt][ks][jj] = (short)f2bf(vv[jj] - bf2f(hb));
            }
        }
    }

    float b1[4][4], b2[4][4];
    int j1[4][4];
#pragma unroll
    for (int rt = 0; rt < 4; ++rt)
#pragma unroll
        for (int i = 0; i < 4; ++i) {
            b1[rt][i] = 3.4e38f; b2[rt][i] = 3.4e38f; j1[rt][i] = 0;
        }

    for (int ct = 0; ct < 16; ++ct) {
        int col = cbase + ct * 16 + lr;
        const unsigned short* ph = &cb_hi[(size_t)col * LAT_N + lg * 8];
        const unsigned short* pl = &cb_lo[(size_t)col * LAT_N + lg * 8];
        s8v bh0 = *reinterpret_cast<const s8v*>(ph);
        s8v bh1 = *reinterpret_cast<const s8v*>(ph + 32);
        s8v bl0 = *reinterpret_cast<const s8v*>(pl);
        s8v bl1 = *reinterpret_cast<const s8v*>(pl + 32);
        float cn = cnorm[col];
#pragma unroll
        for (int rt = 0; rt < 4; ++rt) {
            f4v acc = {0.f, 0.f, 0.f, 0.f};
            acc = __builtin_amdgcn_mfma_f32_16x16x32_bf16(a_hi[rt][0], bh0, acc, 0, 0, 0);
            acc = __builtin_amdgcn_mfma_f32_16x16x32_bf16(a_hi[rt][1], bh1, acc, 0, 0, 0);
            acc = __builtin_amdgcn_mfma_f32_16x16x32_bf16(a_lo[rt][0], bh0, acc, 0, 0, 0);
            acc = __builtin_amdgcn_mfma_f32_16x16x32_bf16(a_lo[rt][1], bh1, acc, 0, 0, 0);
            acc = __builtin_amdgcn_mfma_f32_16x16x32_bf16(a_hi[rt][0], bl0, acc, 0, 0, 0);
            acc = __builtin_amdgcn_mfma_f32_16x16x32_bf16(a_hi[rt][1], bl1, acc, 0, 0, 0);
#pragma unroll
            for (int i = 0; i < 4; ++i) {
                float d = fmaf(-2.f, acc[i], cn);
                if (d < b1[rt][i]) {
                    b2[rt][i] = b1[rt][i];
                    b1[rt][i] = d;
                    j1[rt][i] = col;
                } else if (d < b2[rt][i]) {
                    b2[rt][i] = d;
                }
            }
        }
    }

#pragma unroll
    for (int off = 1; off < 16; off <<= 1) {
#pragma unroll
        for (int rt = 0; rt < 4; ++rt)
#pragma unroll
            for (int i = 0; i < 4; ++i) {
                float o1 = __shfl_xor(b1[rt][i], off);
                float o2 = __shfl_xor(b2[rt][i], off);
                int oj = __shfl_xor(j1[rt][i], off);
                float nb2 = fminf(fmaxf(b1[rt][i], o1), fminf(b2[rt][i], o2));
                if (o1 < b1[rt][i] ||
                    (o1 == b1[rt][i] && oj < j1[rt][i])) {
                    b1[rt][i] = o1;
                    j1[rt][i] = oj;
                }
                b2[rt][i] = nb2;
            }
    }
    if (lr == 0) {
#pragma unroll
        for (int rt = 0; rt < 4; ++rt)
#pragma unroll
            for (int i = 0; i < 4; ++i) {
                int row = rbase + rt * 16 + lg * 4 + i;
                cand[(size_t)row * 8 + cblk] = make_float4(
                    b1[rt][i], __int_as_float(j1[rt][i]), b2[rt][i], 0.f);
            }
    }
}

// merge 8 col-block candidates/row; flag near-ties for exact repair
__global__ __launch_bounds__(256) void vq_merge(
    const float4* __restrict__ cand, float* __restrict__ idxf,
    int* __restrict__ rlist, int* __restrict__ rcnt)
{
    int row = blockIdx.x * 256 + threadIdx.x;
    const float4* c = &cand[(size_t)row * 8];
    float4 c0 = c[0];
    float b1 = c0.x, b2 = c0.z;
    int j1 = __float_as_int(c0.y);
#pragma unroll
    for (int t = 1; t < 8; ++t) {
        float4 ct = c[t];
        float o1 = ct.x, o2 = ct.z;
        int oj = __float_as_int(ct.y);
        float nb2 = fminf(fmaxf(b1, o1), fminf(b2, o2));
        if (o1 < b1 || (o1 == b1 && oj < j1)) { b1 = o1; j1 = oj; }
        b2 = nb2;
    }
    idxf[row] = (float)j1;
    if (!(b2 - b1 >= VQ_MARGIN)) {
        int s = atomicAdd(rcnt, 1);
        if (s < B_ROWS) rlist[s] = row;
    }
}

// exact-f32 full-row rescan of flagged rows (register-light)
#define RB 8
__global__ __launch_bounds__(256) void vq_repair(
    const int* __restrict__ rcnt, const int* __restrict__ rlist,
    const float* __restrict__ z, const float* __restrict__ cb,
    const float* __restrict__ cn, float* __restrict__ idxf)
{
    __shared__ float sz[RB][LAT_N];
    __shared__ float rv[256];
    __shared__ int ri[256];
    const int tid = threadIdx.x;
    const int count = min(rcnt[0], B_ROWS);
    if (blockIdx.x * RB >= count) return;
    for (int base = blockIdx.x * RB; base < count; base += gridDim.x * RB) {
        int nr = min(RB, count - base);
        __syncthreads();
        for (int s = tid; s < nr * LAT_N; s += 256) {
            int r = s >> 6, d = s & 63;
            int rr = rlist[base + r];
            rr = ((unsigned)rr < (unsigned)B_ROWS) ? rr : 0;
            sz[r][d] = z[(size_t)rr * LAT_N + d];
        }
        __syncthreads();
        float bv[RB];
        int bj[RB];
#pragma unroll
        for (int r = 0; r < RB; ++r) { bv[r] = 3.4e38f; bj[r] = 0; }
        for (int k = 0; k < K_CB / 256; ++k) {
            int cidx = tid + k * 256;
            float acc[RB];
#pragma unroll
            for (int r = 0; r < RB; ++r) acc[r] = 0.f;
            const float* cp = &cb[(size_t)cidx * LAT_N];
#pragma unroll 2
            for (int d4 = 0; d4 < 16; ++d4) {
                float4 cv = *reinterpret_cast<const float4*>(cp + d4 * 4);
#pragma unroll
                for (int r = 0; r < RB; ++r) {
                    acc[r] = fmaf(sz[r][d4 * 4 + 0], cv.x, acc[r]);
                    acc[r] = fmaf(sz[r][d4 * 4 + 1], cv.y, acc[r]);
                    acc[r] = fmaf(sz[r][d4 * 4 + 2], cv.z, acc[r]);
                    acc[r] = fmaf(sz[r][d4 * 4 + 3], cv.w, acc[r]);
                }
            }
            float cnv = cn[cidx];
#pragma unroll
            for (int r = 0; r < RB; ++r) {
                float d = fmaf(-2.f, acc[r], cnv);
                if (d < bv[r] || (d == bv[r] && cidx < bj[r])) {
                    bv[r] = d; bj[r] = cidx;
                }
            }
        }
        for (int r = 0; r < RB; ++r) {
            if (r >= nr) break;
            rv[tid] = bv[r];
            ri[tid] = bj[r];
            __syncthreads();
            for (int off = 128; off > 0; off >>= 1) {
                if (tid < off) {
                    float ov = rv[tid + off];
                    int oi = ri[tid + off];
                    if (ov < rv[tid] || (ov == rv[tid] && oi < ri[tid])) {
                        rv[tid] = ov; ri[tid] = oi;
                    }
                }
                __syncthreads();
            }
            if (tid == 0) {
                int rr = rlist[base + r];
                if ((unsigned)rr < (unsigned)B_ROWS)
                    idxf[rr] = (float)ri[0];
            }
            __syncthreads();
        }
    }
}

// gather z_q (bf16 hi/lo, from pre-split codebook) + vq-loss partials
__global__ __launch_bounds__(256) void vq_zqloss(
    const float* __restrict__ idxf, const float* __restrict__ z,
    const float* __restrict__ cb,
    const unsigned short* __restrict__ cbhi,
    const unsigned short* __restrict__ cblo,
    unsigned short* __restrict__ zqhi, unsigned short* __restrict__ zqlo,
    float* __restrict__ partials)
{
    __shared__ float red[256];
    int tid = threadIdx.x;
    int row = blockIdx.x * 256 + tid;
    int bj = (int)idxf[row];
    bj = ((unsigned)bj < (unsigned)K_CB) ? bj : 0;
    float sq = 0.f;
#pragma unroll
    for (int lq = 0; lq < 16; ++lq) {
        float4 cv = *reinterpret_cast<const float4*>(&cb[(size_t)bj * LAT_N + lq * 4]);
        float4 zv = *reinterpret_cast<const float4*>(&z[(size_t)row * LAT_N + lq * 4]);
        float d0 = cv.x - zv.x, d1 = cv.y - zv.y;
        float d2 = cv.z - zv.z, d3 = cv.w - zv.w;
        sq = fmaf(d0, d0, sq); sq = fmaf(d1, d1, sq);
        sq = fmaf(d2, d2, sq); sq = fmaf(d3, d3, sq);
    }
    // copy pre-split bf16 rows (64 ushort = 8 x uint4)
    const uint4* gh = reinterpret_cast<const uint4*>(&cbhi[(size_t)bj * LAT_N]);
    const uint4* gl = reinterpret_cast<const uint4*>(&cblo[(size_t)bj * LAT_N]);
    uint4* dh = reinterpret_cast<uint4*>(&zqhi[(size_t)row * LAT_N]);
    uint4* dl = reinterpret_cast<uint4*>(&zqlo[(size_t)row * LAT_N]);
#pragma unroll
    for (int q = 0; q < 8; ++q) { dh[q] = gh[q]; dl[q] = gl[q]; }

    red[tid] = sq;
    __syncthreads();
    for (int off = 128; off > 0; off >>= 1) {
        if (tid < off) red[tid] += red[tid + off];
        __syncthreads();
    }
    if (tid == 0) partials[blockIdx.x] = red[0];
}

__global__ __launch_bounds__(256) void finalize_kernel(
    const float* __restrict__ vqp, int nvq,
    const float* __restrict__ rep, int nre,
    float* __restrict__ vq_out, float* __restrict__ re_out)
{
    __shared__ float s[256];
    int tid = threadIdx.x;
    float a = 0.f;
    for (int i = tid; i < nvq; i += 256) a += vqp[i];
    s[tid] = a;
    __syncthreads();
    for (int off = 128; off > 0; off >>= 1) {
        if (tid < off) s[tid] += s[tid + off];
        __syncthreads();
    }
    if (tid == 0) *vq_out = 1.25f * s[0] / (float)(B_ROWS * LAT_N);
    __syncthreads();
    float b = 0.f;
    for (int i = tid; i < nre; i += 256) b += rep[i];
    s[tid] = b;
    __syncthreads();
    for (int off = 128; off > 0; off >>= 1) {
        if (tid < off) s[tid] += s[tid + off];
        __syncthreads();
    }
    if (tid == 0) *re_out = s[0] / (float)(B_ROWS * D_IN);
}

extern "C" void kernel_launch(void* const* d_in, const int* in_sizes, int n_in,
                              void* d_out, int out_size, void* d_ws, size_t ws_size,
                              hipStream_t stream)
{
    const float* x    = (const float*)d_in[0];
    const float* ew1  = (const float*)d_in[1];
    const float* eb1  = (const float*)d_in[2];
    const float* eg1  = (const float*)d_in[3];
    const float* ebt1 = (const float*)d_in[4];
    const float* em1  = (const float*)d_in[5];
    const float* ev1  = (const float*)d_in[6];
    const float* ew2  = (const float*)d_in[7];
    const float* eb2  = (const float*)d_in[8];
    const float* eg2  = (const float*)d_in[9];
    const float* ebt2 = (const float*)d_in[10];
    const float* em2  = (const float*)d_in[11];
    const float* ev2  = (const float*)d_in[12];
    const float* ew3  = (const float*)d_in[13];
    const float* eb3  = (const float*)d_in[14];
    const float* cb   = (const float*)d_in[15];
    const float* dw1  = (const float*)d_in[16];
    const float* db1  = (const float*)d_in[17];
    const float* dg1  = (const float*)d_in[18];
    const float* dbt1 = (const float*)d_in[19];
    const float* dm1  = (const float*)d_in[20];
    const float* dv1  = (const float*)d_in[21];
    const float* dw2  = (const float*)d_in[22];
    const float* db2  = (const float*)d_in[23];
    const float* dg2  = (const float*)d_in[24];
    const float* dbt2 = (const float*)d_in[25];
    const float* dm2  = (const float*)d_in[26];
    const float* dv2  = (const float*)d_in[27];
    const float* dw3  = (const float*)d_in[28];
    const float* db3  = (const float*)d_in[29];

    float* outf = (float*)d_out;
    const size_t XR_OFF = 0;
    const size_t VQ_OFF = (size_t)B_ROWS * D_IN;
    const size_t IDX_OFF = VQ_OFF + 1;
    const size_t RE_OFF = IDX_OFF + B_ROWS;

    float* wsf = (float*)d_ws;
    size_t off = 0;
    float* buf256 = wsf + off; off += (size_t)B_ROWS * H1_N;   // enc h1 / dec h2 hi+lo
    float* buf128 = wsf + off; off += (size_t)B_ROWS * H2_N;   // enc h2 / dec h1 hi+lo
    float* zbuf   = wsf + off; off += (size_t)B_ROWS * LAT_N;
    float* cnbuf  = wsf + off; off += K_CB;
    float* vqp    = wsf + off; off += 128;
    float* rep    = wsf + off; off += 1024;
    unsigned short* cbhi = (unsigned short*)(wsf + off); off += K_CB * LAT_N / 2;
    unsigned short* cblo = (unsigned short*)(wsf + off); off += K_CB * LAT_N / 2;
    float4* candb = (float4*)(wsf + off); off += (size_t)B_ROWS * 8 * 4;
    int* rcnt  = (int*)(wsf + off); off += 16;
    int* rlist = (int*)(wsf + off); off += B_ROWS;
    unsigned short* w1hi = (unsigned short*)(wsf + off); off += (H2_N * LAT_N) / 2;
    unsigned short* w1lo = (unsigned short*)(wsf + off); off += (H2_N * LAT_N) / 2;
    unsigned short* w2hi = (unsigned short*)(wsf + off); off += (H1_N * H2_N) / 2;
    unsigned short* w2lo = (unsigned short*)(wsf + off); off += (H1_N * H2_N) / 2;
    unsigned short* w3hi = (unsigned short*)(wsf + off); off += (D_IN * H1_N) / 2;
    unsigned short* w3lo = (unsigned short*)(wsf + off); off += (D_IN * H1_N) / 2;
    unsigned short* zqhi = (unsigned short*)(wsf + off); off += (size_t)B_ROWS * LAT_N / 2;
    unsigned short* zqlo = (unsigned short*)(wsf + off); off += (size_t)B_ROWS * LAT_N / 2;

    // decoder activation hi/lo alias the (dead-by-then) encoder buffers
    unsigned short* h1hi = (unsigned short*)buf128;
    unsigned short* h1lo = (unsigned short*)(buf128 + (size_t)B_ROWS * 64);
    unsigned short* h2hi = (unsigned short*)buf256;
    unsigned short* h2lo = (unsigned short*)(buf256 + (size_t)B_ROWS * 128);

    dim3 blk(256);

    vq_prep<<<dim3(K_CB / 256), blk, 0, stream>>>(cb, cbhi, cblo, cnbuf, rcnt);
    wprep<<<dim3((LAT_N * H2_N + 255) / 256), blk, 0, stream>>>(dw1, w1hi, w1lo, LAT_N, H2_N);
    wprep<<<dim3((H2_N * H1_N + 255) / 256), blk, 0, stream>>>(dw2, w2hi, w2lo, H2_N, H1_N);
    wprep<<<dim3((H1_N * D_IN + 255) / 256), blk, 0, stream>>>(dw3, w3hi, w3lo, H1_N, D_IN);

    // encoder (exact f32: z_e feeds the argmin)
    gemm_fused<0, 128><<<dim3(B_ROWS / 128, H1_N / BN), blk, 0, stream>>>(
        x, ew1, eb1, eg1, ebt1, em1, ev1, buf256, D_IN, H1_N);
    gemm_fused<0, 64><<<dim3(B_ROWS / 64, 1), blk, 0, stream>>>(
        buf256, ew2, eb2, eg2, ebt2, em2, ev2, buf128, H1_N, H2_N);
    gemm_fused<1, 64><<<dim3(B_ROWS / 64, 1), blk, 0, stream>>>(
        buf128, ew3, eb3, nullptr, nullptr, nullptr, nullptr, zbuf, H2_N, LAT_N);

    // vector quantization: MFMA top-2 -> merge/flag -> exact repair -> gather
    vq_mfma<<<dim3(1024), blk, 0, stream>>>(zbuf, cbhi, cblo, cnbuf, candb);
    vq_merge<<<dim3(B_ROWS / 256), blk, 0, stream>>>(
        candb, outf + IDX_OFF, rlist, rcnt);
    vq_repair<<<dim3(256), blk, 0, stream>>>(
        rcnt, rlist, zbuf, cb, cnbuf, outf + IDX_OFF);
    vq_zqloss<<<dim3(B_ROWS / 256), blk, 0, stream>>>(
        outf + IDX_OFF, zbuf, cb, cbhi, cblo, zqhi, zqlo, vqp);

    // decoder (bf16x3 MFMA, pre-split activations)
    mfma_gemm<0, LAT_N><<<dim3(B_ROWS / 128, H2_N / 128), blk, 0, stream>>>(
        zqhi, zqlo, w1hi, w1lo, db1, dg1, dbt1, dm1, dv1,
        h1hi, h1lo, nullptr, nullptr, nullptr, H2_N);
    mfma_gemm<0, H2_N><<<dim3(B_ROWS / 128, H1_N / 128), blk, 0, stream>>>(
        h1hi, h1lo, w2hi, w2lo, db2, dg2, dbt2, dm2, dv2,
        h2hi, h2lo, nullptr, nullptr, nullptr, H1_N);
    mfma_gemm<2, H1_N><<<dim3(B_ROWS / 128, D_IN / 128), blk, 0, stream>>>(
        h2hi, h2lo, w3hi, w3lo, db3, nullptr, nullptr, nullptr, nullptr,
        nullptr, nullptr, outf + XR_OFF, x, rep, D_IN);

    finalize_kernel<<<dim3(1), blk, 0, stream>>>(
        vqp, 128, rep, 1024, outf + VQ_OFF, outf + RE_OFF);
}